// Round 5
// baseline (444.907 us; speedup 1.0000x reference)
//
#include <hip/hip_runtime.h>
#include <cstdint>
#include <cstddef>

// ---------------------------------------------------------------------------
// TransformConvCrossAttention: B=4, SQ=SK=2048, D=1024, Kconv=3
// fp16 compute, fp32 MFMA accumulation; fp32 in/out (runtime-verified).
// R15: R13-proven GEMM structure (separate launches, byte-identical kernels)
//      + low-risk launch fusions: 13 -> 10 launches.
//        k_prep  = h_to_f16 + w_to_f16 (one launch, no ws_size dependence)
//        k_convs = dwconv(q) + dwconv(k) + dwconv_t(v) (one launch)
//        scores epilogue reads RAW mask (width from probe flag) -> the
//        mask-packing kernel and its workspace overlay are gone.
//      Dual-descriptor GEMM and tail-layout from R14 dropped (crash suspects).
// ---------------------------------------------------------------------------

#define GLOBAL_AS __attribute__((address_space(1)))
#define LDS_AS    __attribute__((address_space(3)))

typedef _Float16 h8 __attribute__((ext_vector_type(8)));
typedef float    f4_t __attribute__((ext_vector_type(4)));
typedef unsigned short us8 __attribute__((ext_vector_type(8)));

__device__ __forceinline__ float bf2f(unsigned short u) {
    union { unsigned int i; float f; } x; x.i = ((unsigned int)u) << 16; return x.f;
}
__device__ __forceinline__ float rd(const void* p, long i, int isBf) {
    return isBf ? bf2f(((const unsigned short*)p)[i]) : ((const float*)p)[i];
}

// ---------------------------------------------------------------------------
// Probes: blocks 0..15 = dtype sniff per tensor; block 16 = mask width.
struct Probe16 { const unsigned short* p[16]; int n[16]; };

__global__ void k_probes(Probe16 a, const unsigned int* __restrict__ mask,
                         int* __restrict__ flags) {
    if (blockIdx.x < 16) {
        __shared__ int cnt;
        if (threadIdx.x == 0) cnt = 0;
        __syncthreads();
        const unsigned short* s = a.p[blockIdx.x];
        const int n = a.n[blockIdx.x];
        int bad = 0;
        for (int i = threadIdx.x; i < n; i += 256) {
            int e = (s[i] >> 7) & 0xFF;
            if (e >= 0x8F || (e > 0 && e <= 0x60)) bad++;
        }
        atomicAdd(&cnt, bad);
        __syncthreads();
        if (threadIdx.x == 0) flags[blockIdx.x] = (cnt * 4 > n) ? 0 : 1;
    } else {
        __shared__ int vi32, vf32, vbf, vf16;
        if (threadIdx.x == 0) { vi32 = vf32 = vbf = vf16 = 0; }
        __syncthreads();
        int bi32 = 0, bf32 = 0, bbf = 0, bf16c = 0;
        for (int i = threadIdx.x; i < 4096; i += 256) {
            unsigned int w = mask[i];
            if (!(w == 0u || w == 1u)) bi32++;
            if (!(w == 0u || w == 0x3F800000u)) bf32++;
            unsigned int h0 = w & 0xFFFFu, h1 = w >> 16;
            if (!((h0 == 0u || h0 == 0x3F80u) && (h1 == 0u || h1 == 0x3F80u))) bbf++;
            if (!((h0 == 0u || h0 == 0x3C00u) && (h1 == 0u || h1 == 0x3C00u))) bf16c++;
        }
        if (bi32) atomicAdd(&vi32, 1);
        if (bf32) atomicAdd(&vf32, 1);
        if (bbf)  atomicAdd(&vbf, 1);
        if (bf16c) atomicAdd(&vf16, 1);
        __syncthreads();
        if (threadIdx.x == 0) {
            int w;
            if (vi32 == 0) w = 4;
            else if (vf32 == 0) w = 4;
            else if (vbf == 0) w = 2;
            else if (vf16 == 0) w = 2;
            else w = 1;
            flags[16] = w;
        }
    }
}

// ---------------------------------------------------------------------------
// shared device bodies
__device__ __forceinline__ h8 cvt8(const void* src, size_t off8, int isBf) {
    h8 d;
    if (isBf) {
        us8 s = *(const us8*)((const unsigned short*)src + off8 * 8);
#pragma unroll
        for (int u = 0; u < 8; ++u) d[u] = (_Float16)bf2f(s[u]);
    } else {
        const float* f = (const float*)src + off8 * 8;
        f4_t a = *(const f4_t*)f;
        f4_t b = *(const f4_t*)(f + 4);
#pragma unroll
        for (int u = 0; u < 4; ++u) { d[u] = (_Float16)a[u]; d[4 + u] = (_Float16)b[u]; }
    }
    return d;
}

struct Ptr4 { const void* p[4]; };

// ---------------------------------------------------------------------------
// k_prep: fused converts. Grid 10240 x 256 thr:
//   [0, 8192)      qh|mh -> fp16 (2*nH8 = 2,097,152 h8 units, nH8 = 2^20)
//   [8192, 10240)  4 weight mats -> fp16 (4*nW8 = 524,288, nW8 = 2^17)
__global__ void k_prep(const void* __restrict__ qh, const void* __restrict__ mh,
                       _Float16* __restrict__ h16dst,
                       Ptr4 wsrc, _Float16* __restrict__ w16dst,
                       const int* __restrict__ flags) {
    const int bid = blockIdx.x, tid = threadIdx.x;
    if (bid < 8192) {
        int i = bid * 256 + tid;
        int seg = i >> 20, off = i & 1048575;
        h8 d = cvt8(seg ? mh : qh, off, flags[seg]);
        *(h8*)(h16dst + (size_t)i * 8) = d;
    } else {
        int i = (bid - 8192) * 256 + tid;
        int seg = i >> 17, off = i & 131071;
        h8 d = cvt8(wsrc.p[seg], off, flags[2 + seg]);
        *(h8*)(w16dst + (size_t)i * 8) = d;
    }
}

// ---------------------------------------------------------------------------
// Conv param precompute: kern [D,3] -> planar fp16 [3][D]; cbias -> fp16 [D];
// tanh(gate) -> float. One block.
struct ConvSrc { const void* kern[3]; const void* cb[3]; const void* gate[3]; };
__global__ void k_conv_params(ConvSrc p, const int* __restrict__ flags,
                              _Float16* __restrict__ out, float* __restrict__ tg, int D) {
#pragma unroll
    for (int t = 0; t < 3; ++t) {
        const int kIs = flags[6 + t], cIs = flags[13 + t];
        for (int d = threadIdx.x; d < D; d += 256) {
#pragma unroll
            for (int j = 0; j < 3; ++j)
                out[t * 3 * D + j * D + d] = (_Float16)rd(p.kern[t], (long)d * 3 + j, kIs);
            out[9 * D + t * D + d] = (_Float16)rd(p.cb[t], d, cIs);
        }
    }
    if (threadIdx.x < 3) {
        const void* g = p.gate[threadIdx.x];
        float gv = rd(g, 0, ((const unsigned int*)g)[0] == 0u ? 1 : 0);
        tg[threadIdx.x] = tanhf(gv);
    }
}

// ---------------------------------------------------------------------------
// R10 NT GEMM (proven 753 TF class), MTILE x 128 x BK=64, 4 waves/block,
// 24KB LDS -> 4 blocks/CU with __launch_bounds__(256,4).
// MODE 0: fp16 out  MODE 1: fp16 out + bias  MODE 2: fp32 out + bias
template <int MODE, int MTILE>
__global__ __launch_bounds__(256, 4) void k_gemm_nt(
    const _Float16* __restrict__ A, const _Float16* __restrict__ Bm,
    void* __restrict__ Cout,
    const void* __restrict__ bias, const int* __restrict__ biasFlag,
    const void* __restrict__ bias2, const int* __restrict__ biasFlag2,
    int N, int K, long sA, long sB, long sC,
    int NT, int BZ) {

    constexpr int NI = (MTILE == 128) ? 4 : 2;
    constexpr int NCA = MTILE / 32;
    __shared__ __align__(16) _Float16 As[MTILE * 64];
    __shared__ __align__(16) _Float16 Bs[128 * 64];

    const long id = blockIdx.x;
    const int xcd = (int)(id & 7);
    const long local = id >> 3;
    const int col = (int)(local % NT);
    const long g = (local / NT) * 8 + xcd;
    const int bz = (int)(g % BZ);
    const int brow = (int)(g / BZ);

    const int tid  = threadIdx.x;
    const int wave = tid >> 6, lane = tid & 63;
    const int wm = (wave >> 1) * (MTILE / 2), wn = (wave & 1) * 64;
    const int lr = lane & 15, lq = lane >> 4;

    const _Float16* Ab = A + (long)bz * sA + (size_t)brow * MTILE * K;
    const _Float16* Bb = Bm + (long)bz * sB + (size_t)col * 128 * K;

    f4_t acc[NI][4] = {};

    const _Float16* gA[NCA];
    _Float16* lA[NCA];
#pragma unroll
    for (int j = 0; j < NCA; ++j) {
        int c = tid + j * 256;
        int r = c >> 3, s = ((c & 7) - r) & 7;
        gA[j] = Ab + (size_t)r * K + s * 8;
        lA[j] = As + c * 8;
    }
    const _Float16* gB[4];
    _Float16* lB[4];
#pragma unroll
    for (int j = 0; j < 4; ++j) {
        int c = tid + j * 256;
        int r = c >> 3, s = ((c & 7) - r) & 7;
        gB[j] = Bb + (size_t)r * K + s * 8;
        lB[j] = Bs + c * 8;
    }

    for (int kb = 0; kb < K; kb += 64) {
#pragma unroll
        for (int j = 0; j < NCA; ++j)
            __builtin_amdgcn_global_load_lds((void GLOBAL_AS*)(gA[j] + kb), (void LDS_AS*)lA[j], 16, 0, 0);
#pragma unroll
        for (int j = 0; j < 4; ++j)
            __builtin_amdgcn_global_load_lds((void GLOBAL_AS*)(gB[j] + kb), (void LDS_AS*)lB[j], 16, 0, 0);
        __syncthreads();

#pragma unroll
        for (int t = 0; t < 2; ++t) {
            const int fs = ((t * 4 + lq + lr) & 7) * 8;
            h8 af[NI], bfr[4];
#pragma unroll
            for (int i = 0; i < NI; ++i) af[i]  = *(const h8*)&As[(wm + i * 16 + lr) * 64 + fs];
#pragma unroll
            for (int j = 0; j < 4; ++j) bfr[j] = *(const h8*)&Bs[(wn + j * 16 + lr) * 64 + fs];
#pragma unroll
            for (int i = 0; i < NI; ++i)
#pragma unroll
                for (int j = 0; j < 4; ++j)
                    acc[i][j] = __builtin_amdgcn_mfma_f32_16x16x32_f16(af[i], bfr[j], acc[i][j], 0, 0, 0);
        }
        __syncthreads();
    }

    const long row0 = (long)brow * MTILE + wm + lq * 4;
    const long col0 = (long)col * 128 + wn + lr;

    float bv[4];
    if constexpr (MODE != 0) {
        const void* bp = bias; const int* bfp = biasFlag; long boff = 0;
        if (bias2 != nullptr && col * 128 >= (N >> 1)) {
            bp = bias2; bfp = biasFlag2; boff = (long)(N >> 1);
        }
        const int bIs = *bfp;
#pragma unroll
        for (int j = 0; j < 4; ++j) bv[j] = rd(bp, col0 + j * 16 - boff, bIs);
    } else {
#pragma unroll
        for (int j = 0; j < 4; ++j) bv[j] = 0.0f;
    }
    if constexpr (MODE == 2) {
        float* C = (float*)Cout + (long)bz * sC;
#pragma unroll
        for (int i = 0; i < NI; ++i)
#pragma unroll
            for (int j = 0; j < 4; ++j)
#pragma unroll
                for (int r = 0; r < 4; ++r)
                    C[(row0 + i * 16 + r) * (long)N + col0 + j * 16] = acc[i][j][r] + bv[j];
    } else {
        _Float16* C = (_Float16*)Cout + (long)bz * sC;
#pragma unroll
        for (int i = 0; i < NI; ++i)
#pragma unroll
            for (int j = 0; j < 4; ++j)
#pragma unroll
                for (int r = 0; r < 4; ++r) {
                    float v = acc[i][j][r] + bv[j];
                    v = fminf(fmaxf(v, -65000.0f), 65000.0f);
                    C[(row0 + i * 16 + r) * (long)N + col0 + j * 16] = (_Float16)v;
                }
    }
}

// ---------------------------------------------------------------------------
// m201-family pipelined NT GEMM: 256 x 256 x BK=64, 512 thr = 8 waves (2Mx4N),
// wave out 128x64. 128KB LDS, 2 K-tile buffers, 4 phases/K-tile (C-quadrants
// of 16 MFMA), 2 global_load_lds per phase, counted vmcnt(4) at 3/4 phase
// closes (never 0 until final drain), setprio(1) around MFMA, seg-rotation
// swizzle (measured 0 conflicts). Byte-identical to R13 except MODE 3's
// epilogue reads the RAW mask (element width in *mwf: 1/2/4 bytes).
// MODE 1: fp16 out + bias (bias2 = 2nd N-half)   MODE 3: fp16 scores.
template <int MODE>
__global__ __launch_bounds__(512, 2) void k_gemm16(
    const _Float16* __restrict__ A, const _Float16* __restrict__ Bm,
    void* __restrict__ Cout,
    const void* __restrict__ bias, const int* __restrict__ biasFlag,
    const void* __restrict__ bias2, const int* __restrict__ biasFlag2,
    int N, int K, long sA, long sB, long sC,
    float scale, const void* __restrict__ mraw, const int* __restrict__ mwf,
    int NT, int BZ) {

    __shared__ __align__(16) _Float16 AS[2][2][8192];
    __shared__ __align__(16) _Float16 BS[2][2][8192];

    const long id = blockIdx.x;
    const int xcd = (int)(id & 7);
    const long local = id >> 3;
    const int col = (int)(local % NT);
    const long g = (local / NT) * 8 + xcd;
    const int bz = (int)(g % BZ);
    const int brow = (int)(g / BZ);

    const int tid  = threadIdx.x;
    const int wave = tid >> 6, lane = tid & 63;
    const int wr = wave >> 2, wc = wave & 3;
    const int lr = lane & 15, lq = lane >> 4;

    const _Float16* Ab = A + (long)bz * sA + (size_t)brow * 256 * K;
    const _Float16* Bb = Bm + (long)bz * sB + (size_t)col * 256 * K;

    f4_t acc[8][4] = {};

    const _Float16* gAsrc[2][2];
    const _Float16* gBsrc[2][2];
    int lOff[2];
#pragma unroll
    for (int j = 0; j < 2; ++j) {
        int c = tid + j * 512;
        int rho = c >> 3, s = ((c & 7) - rho) & 7;
        lOff[j] = c * 8;
#pragma unroll
        for (int gg = 0; gg < 2; ++gg) {
            int ra = gg * 64 + (rho & 63) + (rho >> 6) * 128;
            gAsrc[gg][j] = Ab + (size_t)ra * K + s * 8;
            int rb = gg * 32 + (rho & 31) + (rho >> 5) * 64;
            gBsrc[gg][j] = Bb + (size_t)rb * K + s * 8;
        }
    }

#define STAGE_A(buf, gg, kb)                                                              \
    do {                                                                                  \
        __builtin_amdgcn_global_load_lds((void GLOBAL_AS*)(gAsrc[gg][0] + (kb)),          \
                                         (void LDS_AS*)&AS[buf][gg][lOff[0]], 16, 0, 0);  \
        __builtin_amdgcn_global_load_lds((void GLOBAL_AS*)(gAsrc[gg][1] + (kb)),          \
                                         (void LDS_AS*)&AS[buf][gg][lOff[1]], 16, 0, 0);  \
    } while (0)
#define STAGE_B(buf, gg, kb)                                                              \
    do {                                                                                  \
        __builtin_amdgcn_global_load_lds((void GLOBAL_AS*)(gBsrc[gg][0] + (kb)),          \
                                         (void LDS_AS*)&BS[buf][gg][lOff[0]], 16, 0, 0);  \
        __builtin_amdgcn_global_load_lds((void GLOBAL_AS*)(gBsrc[gg][1] + (kb)),          \
                                         (void LDS_AS*)&BS[buf][gg][lOff[1]], 16, 0, 0);  \
    } while (0)

    const int nkt = K >> 6;

    STAGE_A(0, 0, 0);
    STAGE_B(0, 0, 0);
    STAGE_B(0, 1, 0);
    STAGE_A(0, 1, 0);
    asm volatile("s_waitcnt vmcnt(4)" ::: "memory");
    __builtin_amdgcn_s_barrier();

    int cur = 0;
    for (int t = 0; t < nkt; ++t) {
        const bool pf = (t + 1) < nkt;
        const long kb = (long)(t + 1) << 6;
        const int nx = cur ^ 1;
        h8 a0[4][2], a1[4][2], b0[2][2], b1[2][2];

        // ---- phase 0: quadrant (0,0) ----
#pragma unroll
        for (int ks = 0; ks < 2; ++ks) {
#pragma unroll
            for (int m = 0; m < 4; ++m) {
                int rho = wr * 64 + m * 16 + lr;
                a0[m][ks] = *(const h8*)&AS[cur][0][rho * 64 + ((ks * 4 + lq + rho) & 7) * 8];
            }
#pragma unroll
            for (int n = 0; n < 2; ++n) {
                int rho = wc * 32 + n * 16 + lr;
                b0[n][ks] = *(const h8*)&BS[cur][0][rho * 64 + ((ks * 4 + lq + rho) & 7) * 8];
            }
        }
        if (pf) STAGE_A(nx, 0, kb);
        __builtin_amdgcn_s_barrier();
        __builtin_amdgcn_s_setprio(1);
#pragma unroll
        for (int ks = 0; ks < 2; ++ks)
#pragma unroll
            for (int m = 0; m < 4; ++m)
#pragma unroll
                for (int n = 0; n < 2; ++n)
                    acc[m][n] = __builtin_amdgcn_mfma_f32_16x16x32_f16(
                        a0[m][ks], b0[n][ks], acc[m][n], 0, 0, 0);
        __builtin_amdgcn_s_setprio(0);
        if (pf) asm volatile("s_waitcnt vmcnt(4)" ::: "memory");
        else    asm volatile("s_waitcnt vmcnt(2)" ::: "memory");
        __builtin_amdgcn_s_barrier();

        // ---- phase 1: quadrant (0,1) ----
#pragma unroll
        for (int ks = 0; ks < 2; ++ks)
#pragma unroll
            for (int n = 0; n < 2; ++n) {
                int rho = wc * 32 + n * 16 + lr;
                b1[n][ks] = *(const h8*)&BS[cur][1][rho * 64 + ((ks * 4 + lq + rho) & 7) * 8];
            }
        if (pf) STAGE_B(nx, 0, kb);
        __builtin_amdgcn_s_barrier();
        __builtin_amdgcn_s_setprio(1);
#pragma unroll
        for (int ks = 0; ks < 2; ++ks)
#pragma unroll
            for (int m = 0; m < 4; ++m)
#pragma unroll
                for (int n = 0; n < 2; ++n)
                    acc[m][2 + n] = __builtin_amdgcn_mfma_f32_16x16x32_f16(
                        a0[m][ks], b1[n][ks], acc[m][2 + n], 0, 0, 0);
        __builtin_amdgcn_s_setprio(0);
        if (pf) asm volatile("s_waitcnt vmcnt(4)" ::: "memory");
        else    asm volatile("s_waitcnt vmcnt(0)" ::: "memory");
        __builtin_amdgcn_s_barrier();

        // ---- phase 2: quadrant (1,1) ----
#pragma unroll
        for (int ks = 0; ks < 2; ++ks)
#pragma unroll
            for (int m = 0; m < 4; ++m) {
                int rho = wr * 64 + m * 16 + lr;
                a1[m][ks] = *(const h8*)&AS[cur][1][rho * 64 + ((ks * 4 + lq + rho) & 7) * 8];
            }
        if (pf) STAGE_B(nx, 1, kb);
        __builtin_amdgcn_s_barrier();
        __builtin_amdgcn_s_setprio(1);
#pragma unroll
        for (int ks = 0; ks < 2; ++ks)
#pragma unroll
            for (int m = 0; m < 4; ++m)
#pragma unroll
                for (int n = 0; n < 2; ++n)
                    acc[4 + m][2 + n] = __builtin_amdgcn_mfma_f32_16x16x32_f16(
                        a1[m][ks], b1[n][ks], acc[4 + m][2 + n], 0, 0, 0);
        __builtin_amdgcn_s_setprio(0);
        __builtin_amdgcn_s_barrier();

        // ---- phase 3: quadrant (1,0) ----
#pragma unroll
        for (int ks = 0; ks < 2; ++ks)
#pragma unroll
            for (int n = 0; n < 2; ++n) {
                int rho = wc * 32 + n * 16 + lr;
                b0[n][ks] = *(const h8*)&BS[cur][0][rho * 64 + ((ks * 4 + lq + rho) & 7) * 8];
            }
        if (pf) STAGE_A(nx, 1, kb);
        __builtin_amdgcn_s_barrier();
        __builtin_amdgcn_s_setprio(1);
#pragma unroll
        for (int ks = 0; ks < 2; ++ks)
#pragma unroll
            for (int m = 0; m < 4; ++m)
#pragma unroll
                for (int n = 0; n < 2; ++n)
                    acc[4 + m][n] = __builtin_amdgcn_mfma_f32_16x16x32_f16(
                        a1[m][ks], b0[n][ks], acc[4 + m][n], 0, 0, 0);
        __builtin_amdgcn_s_setprio(0);
        if (pf) asm volatile("s_waitcnt vmcnt(4)" ::: "memory");
        __builtin_amdgcn_s_barrier();
        cur = nx;
    }
#undef STAGE_A
#undef STAGE_B

    const long row0 = (long)brow * 256 + wr * 128 + lq * 4;
    const long col0 = (long)col * 256 + wc * 64 + lr;

    if constexpr (MODE == 3) {
        const int mw = *mwf;
        _Float16* C = (_Float16*)Cout + (long)bz * sC;
#pragma unroll
        for (int i = 0; i < 8; ++i)
#pragma unroll
            for (int j = 0; j < 4; ++j)
#pragma unroll
                for (int r = 0; r < 4; ++r) {
                    long row = row0 + i * 16 + r;
                    long ccol = col0 + j * 16;
                    long mi = row * (long)N + ccol;
                    bool keep;
                    if (mw == 4)      keep = ((const unsigned int*)mraw)[mi] != 0u;
                    else if (mw == 2) keep = ((const unsigned short*)mraw)[mi] != 0;
                    else              keep = ((const unsigned char*)mraw)[mi] != 0;
                    float v = acc[i][j][r] * scale;
                    v = fminf(fmaxf(v, -60000.0f), 60000.0f);
                    C[row * (long)N + ccol] = (_Float16)(keep ? v : -60000.0f);
                }
    } else {
        float bv[4];
        {
            const void* bp = bias; const int* bfp = biasFlag; long boff = 0;
            if (bias2 != nullptr && col * 256 >= (N >> 1)) {
                bp = bias2; bfp = biasFlag2; boff = (long)(N >> 1);
            }
            const int bIs = *bfp;
#pragma unroll
            for (int j = 0; j < 4; ++j) bv[j] = rd(bp, col0 + j * 16 - boff, bIs);
        }
        _Float16* C = (_Float16*)Cout + (long)bz * sC;
#pragma unroll
        for (int i = 0; i < 8; ++i)
#pragma unroll
            for (int j = 0; j < 4; ++j)
#pragma unroll
                for (int r = 0; r < 4; ++r) {
                    float v = acc[i][j][r] + bv[j];
                    v = fminf(fmaxf(v, -65000.0f), 65000.0f);
                    C[(row0 + i * 16 + r) * (long)N + col0 + j * 16] = (_Float16)v;
                }
    }
}

// ---------------------------------------------------------------------------
// Fused conv launch: blocks [0,8192) = dwconv (q then k), 2 rows/block @256thr;
// blocks [8192,10240) = dwconv_v + transpose. Planar fp16 params.
struct ConvP {
    const _Float16* x; int xs; _Float16* y;
    const _Float16* kp; const _Float16* cb; const float* tg;
};
__global__ void k_convs(ConvP p0, ConvP p1,
                        const _Float16* __restrict__ xv, int xvs,
                        _Float16* __restrict__ vt,
                        const _Float16* __restrict__ kpv,
                        const _Float16* __restrict__ cbv,
                        const float* __restrict__ tgv,
                        int S, int SK, int D) {
    __shared__ _Float16 T[64][65];
    const int bid = blockIdx.x, tid = threadIdx.x;
    h8 zero;
#pragma unroll
    for (int u = 0; u < 8; ++u) zero[u] = (_Float16)0.0f;

    if (bid < 8192) {
        const ConvP& p = (bid >= 4096) ? p1 : p0;
        int l = bid & 4095;
        int b = l >> 10, sp = l & 1023;
        int s = sp * 2 + (tid >> 7);
        int d0 = (tid & 127) * 8;
        const size_t xb = ((size_t)b * S + s) * p.xs + d0;
        const size_t yb = ((size_t)b * S + s) * D + d0;
        h8 xc = *(const h8*)(p.x + xb);
        h8 xp = (s > 0)     ? *(const h8*)(p.x + xb - p.xs) : zero;
        h8 xn = (s < S - 1) ? *(const h8*)(p.x + xb + p.xs) : zero;
        h8 k0 = *(const h8*)(p.kp + 0 * D + d0);
        h8 k1 = *(const h8*)(p.kp + 1 * D + d0);
        h8 k2 = *(const h8*)(p.kp + 2 * D + d0);
        h8 cb = *(const h8*)(p.cb + d0);
        float tg = *p.tg;
        h8 o;
#pragma unroll
        for (int u = 0; u < 8; ++u) {
            float cv = (float)xp[u] * (float)k0[u] + (float)xc[u] * (float)k1[u] +
                       (float)xn[u] * (float)k2[u] + (float)cb[u];
            float v = (float)xc[u] + tg * cv;
            o[u] = (_Float16)fminf(fmaxf(v, -65000.0f), 65000.0f);
        }
        *(h8*)(p.y + yb) = o;
    } else {
        int l = bid - 8192;
        int bx = l & 31, by = (l >> 5) & 15, b = l >> 9;
        int s0 = bx * 64, d0 = by * 64;
        float tg = *tgv;
#pragma unroll
        for (int it = 0; it < 2; ++it) {
            int idx = it * 256 + tid;
            int r = idx >> 3, c = (idx & 7) * 8;
            int s = s0 + r;
            const size_t xb = ((size_t)b * SK + s) * xvs + d0 + c;
            h8 xc = *(const h8*)(xv + xb);
            h8 xp = (s > 0)      ? *(const h8*)(xv + xb - xvs) : zero;
            h8 xn = (s < SK - 1) ? *(const h8*)(xv + xb + xvs) : zero;
            h8 k0 = *(const h8*)(kpv + 0 * D + d0 + c);
            h8 k1 = *(const h8*)(kpv + 1 * D + d0 + c);
            h8 k2 = *(const h8*)(kpv + 2 * D + d0 + c);
            h8 cb = *(const h8*)(cbv + d0 + c);
#pragma unroll
            for (int u = 0; u < 8; ++u) {
                float cv = (float)xp[u] * (float)k0[u] + (float)xc[u] * (float)k1[u] +
                           (float)xn[u] * (float)k2[u] + (float)cb[u];
                float v = (float)xc[u] + tg * cv;
                T[r][c + u] = (_Float16)fminf(fmaxf(v, -65000.0f), 65000.0f);
            }
        }
        __syncthreads();
#pragma unroll
        for (int it = 0; it < 2; ++it) {
            int idx = it * 256 + tid;
            int dr = idx >> 3, c = (idx & 7) * 8;
            h8 o;
#pragma unroll
            for (int u = 0; u < 8; ++u) o[u] = T[c + u][dr];
            *(h8*)(vt + ((size_t)b * D + d0 + dr) * SK + s0 + c) = o;
        }
    }
}

// ---------------------------------------------------------------------------
// Row softmax over SK=2048 fp16 scores; one 256-thread block per row.
__global__ __launch_bounds__(256) void k_softmax(const _Float16* __restrict__ sc,
                                                 _Float16* __restrict__ pr, int SK) {
    const long row = blockIdx.x;
    const int tid = threadIdx.x, lane = tid & 63, wave = tid >> 6;
    h8 v = *(const h8*)(sc + row * (long)SK + tid * 8);
    float f[8]; float mx = -3.0e38f;
#pragma unroll
    for (int u = 0; u < 8; ++u) { f[u] = (float)v[u]; mx = fmaxf(mx, f[u]); }
#pragma unroll
    for (int o = 32; o > 0; o >>= 1) mx = fmaxf(mx, __shfl_xor(mx, o, 64));
    __shared__ float red[8];
    if (lane == 0) red[wave] = mx;
    __syncthreads();
    mx = fmaxf(fmaxf(red[0], red[1]), fmaxf(red[2], red[3]));
    float sum = 0.0f;
#pragma unroll
    for (int u = 0; u < 8; ++u) { f[u] = __expf(f[u] - mx); sum += f[u]; }
#pragma unroll
    for (int o = 32; o > 0; o >>= 1) sum += __shfl_xor(sum, o, 64);
    if (lane == 0) red[4 + wave] = sum;
    __syncthreads();
    sum = red[4] + red[5] + red[6] + red[7];
    float inv = 1.0f / sum;
    h8 o8;
#pragma unroll
    for (int u = 0; u < 8; ++u) o8[u] = (_Float16)(f[u] * inv);
    *(h8*)(pr + row * (long)SK + tid * 8) = o8;
}

// ---------------------------------------------------------------------------
extern "C" void kernel_launch(void* const* d_in, const int* in_sizes, int n_in,
                              void* d_out, int out_size, void* d_ws, size_t ws_size,
                              hipStream_t stream) {
    const int Bn = 4, SQ = 2048, SK = 2048, D = 1024;
    const size_t nQ = (size_t)Bn * SQ * D;   // 8,388,608

    const void* qh = d_in[0];
    const void* mh = d_in[1];
    const void* mask = d_in[2];
    const void* q_w = d_in[3];
    const void* q_b = d_in[4];
    const void* k_w = d_in[5];
    const void* k_b = d_in[6];
    const void* v_w = d_in[7];
    const void* v_b = d_in[8];
    const void* o_w = d_in[9];
    const void* o_b = d_in[10];
    const void* q_kern = d_in[11];
    const void* q_cb   = d_in[12];
    const void* q_g    = d_in[13];
    const void* k_kern = d_in[14];
    const void* k_cb   = d_in[15];
    const void* k_g    = d_in[16];
    const void* v_kern = d_in[17];
    const void* v_cb   = d_in[18];
    const void* v_g    = d_in[19];

    // ---- workspace layout (lifetime-overlaid, R13-proven addresses) ----
    // [0,33.5MB)        scores -> attn_out
    // [33.5,41.9MB)     w16 x4; after kv-proj: conv params overlay slot 2
    // [41.9,92.3MB)     lin_q + lin_kv; probs overlays after convs
    // [92.3,125.8MB)    qh16/mh16 staging -> conv_q, conv_k
    // [125.8,142.6MB)   vt  (must NOT alias lin_kv)
    // [142.6MB+)        flags
    char* ws = (char*)d_ws;
    _Float16* scores   = (_Float16*)(ws + 0);
    _Float16* attn_out = (_Float16*)(ws + 0);
    _Float16* w16      = (_Float16*)(ws + 33554432);
    _Float16* par16    = (_Float16*)(ws + 37748736);
    float*    tgf      = (float*)(ws + 37748736 + 12 * 1024 * 2);
    _Float16* lin      = (_Float16*)(ws + 41943040);
    _Float16* lin_q    = lin;
    _Float16* lin_kv   = lin + nQ;
    _Float16* probs    = lin;
    _Float16* conv     = (_Float16*)(ws + 92274688);
    _Float16* qh16     = conv;
    _Float16* mh16     = conv + nQ;
    _Float16* vt       = (_Float16*)(ws + 125829120);
    int*      flags    = (int*)(ws + 142606336);

    // 0. probes
    Probe16 pa;
    const void* pp[16] = {qh, mh, q_w, k_w, v_w, o_w, q_kern, k_kern, v_kern,
                          q_b, k_b, v_b, o_b, q_cb, k_cb, v_cb};
    const int   pn[16] = {2048, 2048, 2048, 2048, 2048, 2048, 3072, 3072, 3072,
                          1024, 1024, 1024, 1024, 1024, 1024, 1024};
    for (int i = 0; i < 16; ++i) { pa.p[i] = (const unsigned short*)pp[i]; pa.n[i] = pn[i]; }
    k_probes<<<17, 256, 0, stream>>>(pa, (const unsigned int*)mask, flags);

    // 1. fused converts -> fp16
    Ptr4 wp; wp.p[0] = q_w; wp.p[1] = k_w; wp.p[2] = v_w; wp.p[3] = o_w;
    k_prep<<<10240, 256, 0, stream>>>(qh, mh, qh16, wp, w16, flags);

    // 2. projections (R13-proven launches)
    k_gemm_nt<1, 64><<<dim3(1024), 256, 0, stream>>>(
        qh16, w16, lin_q, q_b, flags + 9, nullptr, nullptr,
        D, D, 0, 0, 0, 8, 1);
    k_gemm16<1><<<dim3(256), 512, 0, stream>>>(
        mh16, w16 + (size_t)D * D, lin_kv, k_b, flags + 10, v_b, flags + 11,
        2 * D, D, 0, 0, 0, 1.0f, nullptr, nullptr, 8, 1);

    // 2b. conv params into the now-dead w16 slot 2
    ConvSrc cs;
    cs.kern[0] = q_kern; cs.kern[1] = k_kern; cs.kern[2] = v_kern;
    cs.cb[0] = q_cb; cs.cb[1] = k_cb; cs.cb[2] = v_cb;
    cs.gate[0] = q_g; cs.gate[1] = k_g; cs.gate[2] = v_g;
    k_conv_params<<<1, 256, 0, stream>>>(cs, flags, par16, tgf, D);

    // 3. all three gated depthwise convs in one launch
    ConvP cq{lin_q, D, conv + 0 * nQ, par16 + 0 * 3 * D, par16 + 9 * D + 0 * D, tgf + 0};
    ConvP ck{lin_kv, 2 * D, conv + 1 * nQ, par16 + 1 * 3 * D, par16 + 9 * D + 1 * D, tgf + 1};
    k_convs<<<dim3(10240), 256, 0, stream>>>(
        cq, ck, lin_kv + D, 2 * D, vt, par16 + 2 * 3 * D, par16 + 9 * D + 2 * D, tgf + 2,
        SQ, SK, D);

    // 5. scores: per-batch M=2048 (8 tiles), N=2048 (NT=8), BZ=4 -> 256 blocks;
    //    raw-mask read in epilogue (width from flags[16])
    k_gemm16<3><<<dim3(256), 512, 0, stream>>>(
        conv + 0 * nQ, conv + 1 * nQ, scores, nullptr, nullptr, nullptr, nullptr,
        SK, D, (long)SQ * D, (long)SK * D, (long)SQ * SK, 0.03125f, mask, flags + 16, 8, 4);

    // 6. softmax
    k_softmax<<<Bn * SQ, 256, 0, stream>>>(scores, probs, SK);

    // 7. attn @ v: per-batch M=2048(64:32), N=1024 (NT=8), BZ=4 -> 1024 blocks
    k_gemm_nt<0, 64><<<dim3(1024), 256, 0, stream>>>(
        probs, vt, attn_out, nullptr, nullptr, nullptr, nullptr,
        D, SK, (long)SQ * SK, (long)D * SK, (long)SQ * D, 8, 4);

    // 8. out-proj: M=8192(64:128), N=1024 (NT=8), BZ=1 -> 1024 blocks, fp32 out
    k_gemm_nt<2, 64><<<dim3(1024), 256, 0, stream>>>(
        attn_out, w16 + 3 * (size_t)D * D, d_out, o_b, flags + 12, nullptr, nullptr,
        D, D, 0, 0, 0, 8, 1);

    (void)in_sizes; (void)n_in; (void)out_size; (void)ws_size;
}

// Round 6
// 393.753 us; speedup vs baseline: 1.1299x; 1.1299x over previous
//
#include <hip/hip_runtime.h>
#include <cstdint>
#include <cstddef>

// ---------------------------------------------------------------------------
// TransformConvCrossAttention: B=4, SQ=SK=2048, D=1024, Kconv=3
// fp16 compute, fp32 MFMA accumulation; fp32 in/out (runtime-verified).
// R16: R15 + mask moved from the scores GEMM epilogue into k_softmax
//      (coalesced row read, +16.8MB coalesced vs 67MB scattered = the R15
//      regression). Scores epilogue = pure scale+clamp, no mask read.
//      k_conv_params folded into k_prep (block 10240); par16/tgf relocated
//      to the tail of the scores region (written step1, read step3,
//      clobbered by scores only at step5). Launches: 10 -> 9.
// ---------------------------------------------------------------------------

#define GLOBAL_AS __attribute__((address_space(1)))
#define LDS_AS    __attribute__((address_space(3)))

typedef _Float16 h8 __attribute__((ext_vector_type(8)));
typedef float    f4_t __attribute__((ext_vector_type(4)));
typedef unsigned short us8 __attribute__((ext_vector_type(8)));

__device__ __forceinline__ float bf2f(unsigned short u) {
    union { unsigned int i; float f; } x; x.i = ((unsigned int)u) << 16; return x.f;
}
__device__ __forceinline__ float rd(const void* p, long i, int isBf) {
    return isBf ? bf2f(((const unsigned short*)p)[i]) : ((const float*)p)[i];
}

// ---------------------------------------------------------------------------
// Probes: blocks 0..15 = dtype sniff per tensor; block 16 = mask width.
struct Probe16 { const unsigned short* p[16]; int n[16]; };

__global__ void k_probes(Probe16 a, const unsigned int* __restrict__ mask,
                         int* __restrict__ flags) {
    if (blockIdx.x < 16) {
        __shared__ int cnt;
        if (threadIdx.x == 0) cnt = 0;
        __syncthreads();
        const unsigned short* s = a.p[blockIdx.x];
        const int n = a.n[blockIdx.x];
        int bad = 0;
        for (int i = threadIdx.x; i < n; i += 256) {
            int e = (s[i] >> 7) & 0xFF;
            if (e >= 0x8F || (e > 0 && e <= 0x60)) bad++;
        }
        atomicAdd(&cnt, bad);
        __syncthreads();
        if (threadIdx.x == 0) flags[blockIdx.x] = (cnt * 4 > n) ? 0 : 1;
    } else {
        __shared__ int vi32, vf32, vbf, vf16;
        if (threadIdx.x == 0) { vi32 = vf32 = vbf = vf16 = 0; }
        __syncthreads();
        int bi32 = 0, bf32 = 0, bbf = 0, bf16c = 0;
        for (int i = threadIdx.x; i < 4096; i += 256) {
            unsigned int w = mask[i];
            if (!(w == 0u || w == 1u)) bi32++;
            if (!(w == 0u || w == 0x3F800000u)) bf32++;
            unsigned int h0 = w & 0xFFFFu, h1 = w >> 16;
            if (!((h0 == 0u || h0 == 0x3F80u) && (h1 == 0u || h1 == 0x3F80u))) bbf++;
            if (!((h0 == 0u || h0 == 0x3C00u) && (h1 == 0u || h1 == 0x3C00u))) bf16c++;
        }
        if (bi32) atomicAdd(&vi32, 1);
        if (bf32) atomicAdd(&vf32, 1);
        if (bbf)  atomicAdd(&vbf, 1);
        if (bf16c) atomicAdd(&vf16, 1);
        __syncthreads();
        if (threadIdx.x == 0) {
            int w;
            if (vi32 == 0) w = 4;
            else if (vf32 == 0) w = 4;
            else if (vbf == 0) w = 2;
            else if (vf16 == 0) w = 2;
            else w = 1;
            flags[16] = w;
        }
    }
}

// ---------------------------------------------------------------------------
// shared device bodies
__device__ __forceinline__ h8 cvt8(const void* src, size_t off8, int isBf) {
    h8 d;
    if (isBf) {
        us8 s = *(const us8*)((const unsigned short*)src + off8 * 8);
#pragma unroll
        for (int u = 0; u < 8; ++u) d[u] = (_Float16)bf2f(s[u]);
    } else {
        const float* f = (const float*)src + off8 * 8;
        f4_t a = *(const f4_t*)f;
        f4_t b = *(const f4_t*)(f + 4);
#pragma unroll
        for (int u = 0; u < 4; ++u) { d[u] = (_Float16)a[u]; d[4 + u] = (_Float16)b[u]; }
    }
    return d;
}

struct Ptr4 { const void* p[4]; };
struct ConvSrc { const void* kern[3]; const void* cb[3]; const void* gate[3]; };

// ---------------------------------------------------------------------------
// k_prep: fused converts + conv params. Grid 10241 x 256 thr:
//   [0, 8192)      qh|mh -> fp16 (2*nH8 = 2,097,152 h8 units, nH8 = 2^20)
//   [8192, 10240)  4 weight mats -> fp16 (4*nW8 = 524,288, nW8 = 2^17)
//   [10240]        conv params: kern [D,3] -> planar fp16 [3][D]; cbias;
//                  tanh(gate) -> float
__global__ void k_prep(const void* __restrict__ qh, const void* __restrict__ mh,
                       _Float16* __restrict__ h16dst,
                       Ptr4 wsrc, _Float16* __restrict__ w16dst,
                       ConvSrc cs, _Float16* __restrict__ par16,
                       float* __restrict__ tgf,
                       const int* __restrict__ flags) {
    const int bid = blockIdx.x, tid = threadIdx.x;
    if (bid < 8192) {
        int i = bid * 256 + tid;
        int seg = i >> 20, off = i & 1048575;
        h8 d = cvt8(seg ? mh : qh, off, flags[seg]);
        *(h8*)(h16dst + (size_t)i * 8) = d;
    } else if (bid < 10240) {
        int i = (bid - 8192) * 256 + tid;
        int seg = i >> 17, off = i & 131071;
        h8 d = cvt8(wsrc.p[seg], off, flags[2 + seg]);
        *(h8*)(w16dst + (size_t)i * 8) = d;
    } else {
        const int D = 1024;
#pragma unroll
        for (int t = 0; t < 3; ++t) {
            const int kIs = flags[6 + t], cIs = flags[13 + t];
            for (int d = tid; d < D; d += 256) {
#pragma unroll
                for (int j = 0; j < 3; ++j)
                    par16[t * 3 * D + j * D + d] = (_Float16)rd(cs.kern[t], (long)d * 3 + j, kIs);
                par16[9 * D + t * D + d] = (_Float16)rd(cs.cb[t], d, cIs);
            }
        }
        if (tid < 3) {
            const void* g = cs.gate[tid];
            float gv = rd(g, 0, ((const unsigned int*)g)[0] == 0u ? 1 : 0);
            tgf[tid] = tanhf(gv);
        }
    }
}

// ---------------------------------------------------------------------------
// R10 NT GEMM (proven 753 TF class), MTILE x 128 x BK=64, 4 waves/block,
// 24KB LDS -> 4 blocks/CU with __launch_bounds__(256,4).
// MODE 0: fp16 out  MODE 1: fp16 out + bias  MODE 2: fp32 out + bias
template <int MODE, int MTILE>
__global__ __launch_bounds__(256, 4) void k_gemm_nt(
    const _Float16* __restrict__ A, const _Float16* __restrict__ Bm,
    void* __restrict__ Cout,
    const void* __restrict__ bias, const int* __restrict__ biasFlag,
    const void* __restrict__ bias2, const int* __restrict__ biasFlag2,
    int N, int K, long sA, long sB, long sC,
    int NT, int BZ) {

    constexpr int NI = (MTILE == 128) ? 4 : 2;
    constexpr int NCA = MTILE / 32;
    __shared__ __align__(16) _Float16 As[MTILE * 64];
    __shared__ __align__(16) _Float16 Bs[128 * 64];

    const long id = blockIdx.x;
    const int xcd = (int)(id & 7);
    const long local = id >> 3;
    const int col = (int)(local % NT);
    const long g = (local / NT) * 8 + xcd;
    const int bz = (int)(g % BZ);
    const int brow = (int)(g / BZ);

    const int tid  = threadIdx.x;
    const int wave = tid >> 6, lane = tid & 63;
    const int wm = (wave >> 1) * (MTILE / 2), wn = (wave & 1) * 64;
    const int lr = lane & 15, lq = lane >> 4;

    const _Float16* Ab = A + (long)bz * sA + (size_t)brow * MTILE * K;
    const _Float16* Bb = Bm + (long)bz * sB + (size_t)col * 128 * K;

    f4_t acc[NI][4] = {};

    const _Float16* gA[NCA];
    _Float16* lA[NCA];
#pragma unroll
    for (int j = 0; j < NCA; ++j) {
        int c = tid + j * 256;
        int r = c >> 3, s = ((c & 7) - r) & 7;
        gA[j] = Ab + (size_t)r * K + s * 8;
        lA[j] = As + c * 8;
    }
    const _Float16* gB[4];
    _Float16* lB[4];
#pragma unroll
    for (int j = 0; j < 4; ++j) {
        int c = tid + j * 256;
        int r = c >> 3, s = ((c & 7) - r) & 7;
        gB[j] = Bb + (size_t)r * K + s * 8;
        lB[j] = Bs + c * 8;
    }

    for (int kb = 0; kb < K; kb += 64) {
#pragma unroll
        for (int j = 0; j < NCA; ++j)
            __builtin_amdgcn_global_load_lds((void GLOBAL_AS*)(gA[j] + kb), (void LDS_AS*)lA[j], 16, 0, 0);
#pragma unroll
        for (int j = 0; j < 4; ++j)
            __builtin_amdgcn_global_load_lds((void GLOBAL_AS*)(gB[j] + kb), (void LDS_AS*)lB[j], 16, 0, 0);
        __syncthreads();

#pragma unroll
        for (int t = 0; t < 2; ++t) {
            const int fs = ((t * 4 + lq + lr) & 7) * 8;
            h8 af[NI], bfr[4];
#pragma unroll
            for (int i = 0; i < NI; ++i) af[i]  = *(const h8*)&As[(wm + i * 16 + lr) * 64 + fs];
#pragma unroll
            for (int j = 0; j < 4; ++j) bfr[j] = *(const h8*)&Bs[(wn + j * 16 + lr) * 64 + fs];
#pragma unroll
            for (int i = 0; i < NI; ++i)
#pragma unroll
                for (int j = 0; j < 4; ++j)
                    acc[i][j] = __builtin_amdgcn_mfma_f32_16x16x32_f16(af[i], bfr[j], acc[i][j], 0, 0, 0);
        }
        __syncthreads();
    }

    const long row0 = (long)brow * MTILE + wm + lq * 4;
    const long col0 = (long)col * 128 + wn + lr;

    float bv[4];
    if constexpr (MODE != 0) {
        const void* bp = bias; const int* bfp = biasFlag; long boff = 0;
        if (bias2 != nullptr && col * 128 >= (N >> 1)) {
            bp = bias2; bfp = biasFlag2; boff = (long)(N >> 1);
        }
        const int bIs = *bfp;
#pragma unroll
        for (int j = 0; j < 4; ++j) bv[j] = rd(bp, col0 + j * 16 - boff, bIs);
    } else {
#pragma unroll
        for (int j = 0; j < 4; ++j) bv[j] = 0.0f;
    }
    if constexpr (MODE == 2) {
        float* C = (float*)Cout + (long)bz * sC;
#pragma unroll
        for (int i = 0; i < NI; ++i)
#pragma unroll
            for (int j = 0; j < 4; ++j)
#pragma unroll
                for (int r = 0; r < 4; ++r)
                    C[(row0 + i * 16 + r) * (long)N + col0 + j * 16] = acc[i][j][r] + bv[j];
    } else {
        _Float16* C = (_Float16*)Cout + (long)bz * sC;
#pragma unroll
        for (int i = 0; i < NI; ++i)
#pragma unroll
            for (int j = 0; j < 4; ++j)
#pragma unroll
                for (int r = 0; r < 4; ++r) {
                    float v = acc[i][j][r] + bv[j];
                    v = fminf(fmaxf(v, -65000.0f), 65000.0f);
                    C[(row0 + i * 16 + r) * (long)N + col0 + j * 16] = (_Float16)v;
                }
    }
}

// ---------------------------------------------------------------------------
// m201-family pipelined NT GEMM: 256 x 256 x BK=64, 512 thr = 8 waves (2Mx4N),
// wave out 128x64. 128KB LDS, 2 K-tile buffers, 4 phases/K-tile (C-quadrants
// of 16 MFMA), 2 global_load_lds per phase, counted vmcnt(4) at 3/4 phase
// closes (never 0 until final drain), setprio(1) around MFMA, seg-rotation
// swizzle (measured 0 conflicts). R13-verified loop.
// MODE 1: fp16 out + bias (bias2 = 2nd N-half)
// MODE 3: fp16 scores, scale+clamp only (mask applied later in softmax)
template <int MODE>
__global__ __launch_bounds__(512, 2) void k_gemm16(
    const _Float16* __restrict__ A, const _Float16* __restrict__ Bm,
    void* __restrict__ Cout,
    const void* __restrict__ bias, const int* __restrict__ biasFlag,
    const void* __restrict__ bias2, const int* __restrict__ biasFlag2,
    int N, int K, long sA, long sB, long sC,
    float scale, int NT, int BZ) {

    __shared__ __align__(16) _Float16 AS[2][2][8192];
    __shared__ __align__(16) _Float16 BS[2][2][8192];

    const long id = blockIdx.x;
    const int xcd = (int)(id & 7);
    const long local = id >> 3;
    const int col = (int)(local % NT);
    const long g = (local / NT) * 8 + xcd;
    const int bz = (int)(g % BZ);
    const int brow = (int)(g / BZ);

    const int tid  = threadIdx.x;
    const int wave = tid >> 6, lane = tid & 63;
    const int wr = wave >> 2, wc = wave & 3;
    const int lr = lane & 15, lq = lane >> 4;

    const _Float16* Ab = A + (long)bz * sA + (size_t)brow * 256 * K;
    const _Float16* Bb = Bm + (long)bz * sB + (size_t)col * 256 * K;

    f4_t acc[8][4] = {};

    const _Float16* gAsrc[2][2];
    const _Float16* gBsrc[2][2];
    int lOff[2];
#pragma unroll
    for (int j = 0; j < 2; ++j) {
        int c = tid + j * 512;
        int rho = c >> 3, s = ((c & 7) - rho) & 7;
        lOff[j] = c * 8;
#pragma unroll
        for (int gg = 0; gg < 2; ++gg) {
            int ra = gg * 64 + (rho & 63) + (rho >> 6) * 128;
            gAsrc[gg][j] = Ab + (size_t)ra * K + s * 8;
            int rb = gg * 32 + (rho & 31) + (rho >> 5) * 64;
            gBsrc[gg][j] = Bb + (size_t)rb * K + s * 8;
        }
    }

#define STAGE_A(buf, gg, kb)                                                              \
    do {                                                                                  \
        __builtin_amdgcn_global_load_lds((void GLOBAL_AS*)(gAsrc[gg][0] + (kb)),          \
                                         (void LDS_AS*)&AS[buf][gg][lOff[0]], 16, 0, 0);  \
        __builtin_amdgcn_global_load_lds((void GLOBAL_AS*)(gAsrc[gg][1] + (kb)),          \
                                         (void LDS_AS*)&AS[buf][gg][lOff[1]], 16, 0, 0);  \
    } while (0)
#define STAGE_B(buf, gg, kb)                                                              \
    do {                                                                                  \
        __builtin_amdgcn_global_load_lds((void GLOBAL_AS*)(gBsrc[gg][0] + (kb)),          \
                                         (void LDS_AS*)&BS[buf][gg][lOff[0]], 16, 0, 0);  \
        __builtin_amdgcn_global_load_lds((void GLOBAL_AS*)(gBsrc[gg][1] + (kb)),          \
                                         (void LDS_AS*)&BS[buf][gg][lOff[1]], 16, 0, 0);  \
    } while (0)

    const int nkt = K >> 6;

    STAGE_A(0, 0, 0);
    STAGE_B(0, 0, 0);
    STAGE_B(0, 1, 0);
    STAGE_A(0, 1, 0);
    asm volatile("s_waitcnt vmcnt(4)" ::: "memory");
    __builtin_amdgcn_s_barrier();

    int cur = 0;
    for (int t = 0; t < nkt; ++t) {
        const bool pf = (t + 1) < nkt;
        const long kb = (long)(t + 1) << 6;
        const int nx = cur ^ 1;
        h8 a0[4][2], a1[4][2], b0[2][2], b1[2][2];

        // ---- phase 0: quadrant (0,0) ----
#pragma unroll
        for (int ks = 0; ks < 2; ++ks) {
#pragma unroll
            for (int m = 0; m < 4; ++m) {
                int rho = wr * 64 + m * 16 + lr;
                a0[m][ks] = *(const h8*)&AS[cur][0][rho * 64 + ((ks * 4 + lq + rho) & 7) * 8];
            }
#pragma unroll
            for (int n = 0; n < 2; ++n) {
                int rho = wc * 32 + n * 16 + lr;
                b0[n][ks] = *(const h8*)&BS[cur][0][rho * 64 + ((ks * 4 + lq + rho) & 7) * 8];
            }
        }
        if (pf) STAGE_A(nx, 0, kb);
        __builtin_amdgcn_s_barrier();
        __builtin_amdgcn_s_setprio(1);
#pragma unroll
        for (int ks = 0; ks < 2; ++ks)
#pragma unroll
            for (int m = 0; m < 4; ++m)
#pragma unroll
                for (int n = 0; n < 2; ++n)
                    acc[m][n] = __builtin_amdgcn_mfma_f32_16x16x32_f16(
                        a0[m][ks], b0[n][ks], acc[m][n], 0, 0, 0);
        __builtin_amdgcn_s_setprio(0);
        if (pf) asm volatile("s_waitcnt vmcnt(4)" ::: "memory");
        else    asm volatile("s_waitcnt vmcnt(2)" ::: "memory");
        __builtin_amdgcn_s_barrier();

        // ---- phase 1: quadrant (0,1) ----
#pragma unroll
        for (int ks = 0; ks < 2; ++ks)
#pragma unroll
            for (int n = 0; n < 2; ++n) {
                int rho = wc * 32 + n * 16 + lr;
                b1[n][ks] = *(const h8*)&BS[cur][1][rho * 64 + ((ks * 4 + lq + rho) & 7) * 8];
            }
        if (pf) STAGE_B(nx, 0, kb);
        __builtin_amdgcn_s_barrier();
        __builtin_amdgcn_s_setprio(1);
#pragma unroll
        for (int ks = 0; ks < 2; ++ks)
#pragma unroll
            for (int m = 0; m < 4; ++m)
#pragma unroll
                for (int n = 0; n < 2; ++n)
                    acc[m][2 + n] = __builtin_amdgcn_mfma_f32_16x16x32_f16(
                        a0[m][ks], b1[n][ks], acc[m][2 + n], 0, 0, 0);
        __builtin_amdgcn_s_setprio(0);
        if (pf) asm volatile("s_waitcnt vmcnt(4)" ::: "memory");
        else    asm volatile("s_waitcnt vmcnt(0)" ::: "memory");
        __builtin_amdgcn_s_barrier();

        // ---- phase 2: quadrant (1,1) ----
#pragma unroll
        for (int ks = 0; ks < 2; ++ks)
#pragma unroll
            for (int m = 0; m < 4; ++m) {
                int rho = wr * 64 + m * 16 + lr;
                a1[m][ks] = *(const h8*)&AS[cur][1][rho * 64 + ((ks * 4 + lq + rho) & 7) * 8];
            }
        if (pf) STAGE_B(nx, 1, kb);
        __builtin_amdgcn_s_barrier();
        __builtin_amdgcn_s_setprio(1);
#pragma unroll
        for (int ks = 0; ks < 2; ++ks)
#pragma unroll
            for (int m = 0; m < 4; ++m)
#pragma unroll
                for (int n = 0; n < 2; ++n)
                    acc[4 + m][2 + n] = __builtin_amdgcn_mfma_f32_16x16x32_f16(
                        a1[m][ks], b1[n][ks], acc[4 + m][2 + n], 0, 0, 0);
        __builtin_amdgcn_s_setprio(0);
        __builtin_amdgcn_s_barrier();

        // ---- phase 3: quadrant (1,0) ----
#pragma unroll
        for (int ks = 0; ks < 2; ++ks)
#pragma unroll
            for (int n = 0; n < 2; ++n) {
                int rho = wc * 32 + n * 16 + lr;
                b0[n][ks] = *(const h8*)&BS[cur][0][rho * 64 + ((ks * 4 + lq + rho) & 7) * 8];
            }
        if (pf) STAGE_A(nx, 1, kb);
        __builtin_amdgcn_s_barrier();
        __builtin_amdgcn_s_setprio(1);
#pragma unroll
        for (int ks = 0; ks < 2; ++ks)
#pragma unroll
            for (int m = 0; m < 4; ++m)
#pragma unroll
                for (int n = 0; n < 2; ++n)
                    acc[4 + m][n] = __builtin_amdgcn_mfma_f32_16x16x32_f16(
                        a1[m][ks], b0[n][ks], acc[4 + m][n], 0, 0, 0);
        __builtin_amdgcn_s_setprio(0);
        if (pf) asm volatile("s_waitcnt vmcnt(4)" ::: "memory");
        __builtin_amdgcn_s_barrier();
        cur = nx;
    }
#undef STAGE_A
#undef STAGE_B

    const long row0 = (long)brow * 256 + wr * 128 + lq * 4;
    const long col0 = (long)col * 256 + wc * 64 + lr;

    if constexpr (MODE == 3) {
        _Float16* C = (_Float16*)Cout + (long)bz * sC;
#pragma unroll
        for (int i = 0; i < 8; ++i)
#pragma unroll
            for (int j = 0; j < 4; ++j)
#pragma unroll
                for (int r = 0; r < 4; ++r) {
                    float v = acc[i][j][r] * scale;
                    v = fminf(fmaxf(v, -60000.0f), 60000.0f);
                    C[(row0 + i * 16 + r) * (long)N + col0 + j * 16] = (_Float16)v;
                }
    } else {
        float bv[4];
        {
            const void* bp = bias; const int* bfp = biasFlag; long boff = 0;
            if (bias2 != nullptr && col * 256 >= (N >> 1)) {
                bp = bias2; bfp = biasFlag2; boff = (long)(N >> 1);
            }
            const int bIs = *bfp;
#pragma unroll
            for (int j = 0; j < 4; ++j) bv[j] = rd(bp, col0 + j * 16 - boff, bIs);
        }
        _Float16* C = (_Float16*)Cout + (long)bz * sC;
#pragma unroll
        for (int i = 0; i < 8; ++i)
#pragma unroll
            for (int j = 0; j < 4; ++j)
#pragma unroll
                for (int r = 0; r < 4; ++r) {
                    float v = acc[i][j][r] + bv[j];
                    v = fminf(fmaxf(v, -65000.0f), 65000.0f);
                    C[(row0 + i * 16 + r) * (long)N + col0 + j * 16] = (_Float16)v;
                }
    }
}

// ---------------------------------------------------------------------------
// Fused conv launch: blocks [0,8192) = dwconv (q then k), 2 rows/block @256thr;
// blocks [8192,10240) = dwconv_v + transpose. Planar fp16 params.
struct ConvP {
    const _Float16* x; int xs; _Float16* y;
    const _Float16* kp; const _Float16* cb; const float* tg;
};
__global__ void k_convs(ConvP p0, ConvP p1,
                        const _Float16* __restrict__ xv, int xvs,
                        _Float16* __restrict__ vt,
                        const _Float16* __restrict__ kpv,
                        const _Float16* __restrict__ cbv,
                        const float* __restrict__ tgv,
                        int S, int SK, int D) {
    __shared__ _Float16 T[64][65];
    const int bid = blockIdx.x, tid = threadIdx.x;
    h8 zero;
#pragma unroll
    for (int u = 0; u < 8; ++u) zero[u] = (_Float16)0.0f;

    if (bid < 8192) {
        const ConvP& p = (bid >= 4096) ? p1 : p0;
        int l = bid & 4095;
        int b = l >> 10, sp = l & 1023;
        int s = sp * 2 + (tid >> 7);
        int d0 = (tid & 127) * 8;
        const size_t xb = ((size_t)b * S + s) * p.xs + d0;
        const size_t yb = ((size_t)b * S + s) * D + d0;
        h8 xc = *(const h8*)(p.x + xb);
        h8 xp = (s > 0)     ? *(const h8*)(p.x + xb - p.xs) : zero;
        h8 xn = (s < S - 1) ? *(const h8*)(p.x + xb + p.xs) : zero;
        h8 k0 = *(const h8*)(p.kp + 0 * D + d0);
        h8 k1 = *(const h8*)(p.kp + 1 * D + d0);
        h8 k2 = *(const h8*)(p.kp + 2 * D + d0);
        h8 cb = *(const h8*)(p.cb + d0);
        float tg = *p.tg;
        h8 o;
#pragma unroll
        for (int u = 0; u < 8; ++u) {
            float cv = (float)xp[u] * (float)k0[u] + (float)xc[u] * (float)k1[u] +
                       (float)xn[u] * (float)k2[u] + (float)cb[u];
            float v = (float)xc[u] + tg * cv;
            o[u] = (_Float16)fminf(fmaxf(v, -65000.0f), 65000.0f);
        }
        *(h8*)(p.y + yb) = o;
    } else {
        int l = bid - 8192;
        int bx = l & 31, by = (l >> 5) & 15, b = l >> 9;
        int s0 = bx * 64, d0 = by * 64;
        float tg = *tgv;
#pragma unroll
        for (int it = 0; it < 2; ++it) {
            int idx = it * 256 + tid;
            int r = idx >> 3, c = (idx & 7) * 8;
            int s = s0 + r;
            const size_t xb = ((size_t)b * SK + s) * xvs + d0 + c;
            h8 xc = *(const h8*)(xv + xb);
            h8 xp = (s > 0)      ? *(const h8*)(xv + xb - xvs) : zero;
            h8 xn = (s < SK - 1) ? *(const h8*)(xv + xb + xvs) : zero;
            h8 k0 = *(const h8*)(kpv + 0 * D + d0 + c);
            h8 k1 = *(const h8*)(kpv + 1 * D + d0 + c);
            h8 k2 = *(const h8*)(kpv + 2 * D + d0 + c);
            h8 cb = *(const h8*)(cbv + d0 + c);
#pragma unroll
            for (int u = 0; u < 8; ++u) {
                float cv = (float)xp[u] * (float)k0[u] + (float)xc[u] * (float)k1[u] +
                           (float)xn[u] * (float)k2[u] + (float)cb[u];
                float v = (float)xc[u] + tg * cv;
                T[r][c + u] = (_Float16)fminf(fmaxf(v, -65000.0f), 65000.0f);
            }
        }
        __syncthreads();
#pragma unroll
        for (int it = 0; it < 2; ++it) {
            int idx = it * 256 + tid;
            int dr = idx >> 3, c = (idx & 7) * 8;
            h8 o;
#pragma unroll
            for (int u = 0; u < 8; ++u) o[u] = T[c + u][dr];
            *(h8*)(vt + ((size_t)b * D + d0 + dr) * SK + s0 + c) = o;
        }
    }
}

// ---------------------------------------------------------------------------
// Row softmax + mask over SK=2048 fp16 scores; one 256-thread block per row.
// Mask row = blockIdx.x & (SQ-1) (mask [SQ,SK] broadcast over batch); element
// width in *mwf (1/2/4 bytes), read coalesced 8 elems/thread. Masked lanes
// forced to -60000 before max/exp (all-masked row -> uniform, matches ref).
__global__ __launch_bounds__(256) void k_softmax(const _Float16* __restrict__ sc,
                                                 _Float16* __restrict__ pr,
                                                 const void* __restrict__ mraw,
                                                 const int* __restrict__ mwf,
                                                 int SK) {
    const long row = blockIdx.x;
    const int tid = threadIdx.x, lane = tid & 63, wave = tid >> 6;
    h8 v = *(const h8*)(sc + row * (long)SK + tid * 8);

    const int mw = *mwf;
    const long mbase = (row & 2047) * (long)SK + tid * 8;
    unsigned int km = 0;   // bit u = keep elem u
    if (mw == 4) {
        const unsigned int* mp = (const unsigned int*)mraw + mbase;
#pragma unroll
        for (int u = 0; u < 8; ++u) km |= (mp[u] != 0u) ? (1u << u) : 0u;
    } else if (mw == 2) {
        const us8 m8 = *(const us8*)((const unsigned short*)mraw + mbase);
#pragma unroll
        for (int u = 0; u < 8; ++u) km |= (m8[u] != 0) ? (1u << u) : 0u;
    } else {
        unsigned long long m8 = *(const unsigned long long*)((const unsigned char*)mraw + mbase);
#pragma unroll
        for (int u = 0; u < 8; ++u) km |= ((m8 >> (8 * u)) & 0xFFull) ? (1u << u) : 0u;
    }

    float f[8]; float mx = -3.0e38f;
#pragma unroll
    for (int u = 0; u < 8; ++u) {
        f[u] = (km & (1u << u)) ? (float)v[u] : -60000.0f;
        mx = fmaxf(mx, f[u]);
    }
#pragma unroll
    for (int o = 32; o > 0; o >>= 1) mx = fmaxf(mx, __shfl_xor(mx, o, 64));
    __shared__ float red[8];
    if (lane == 0) red[wave] = mx;
    __syncthreads();
    mx = fmaxf(fmaxf(red[0], red[1]), fmaxf(red[2], red[3]));
    float sum = 0.0f;
#pragma unroll
    for (int u = 0; u < 8; ++u) { f[u] = __expf(f[u] - mx); sum += f[u]; }
#pragma unroll
    for (int o = 32; o > 0; o >>= 1) sum += __shfl_xor(sum, o, 64);
    if (lane == 0) red[4 + wave] = sum;
    __syncthreads();
    sum = red[4] + red[5] + red[6] + red[7];
    float inv = 1.0f / sum;
    h8 o8;
#pragma unroll
    for (int u = 0; u < 8; ++u) o8[u] = (_Float16)(f[u] * inv);
    *(h8*)(pr + row * (long)SK + tid * 8) = o8;
}

// ---------------------------------------------------------------------------
extern "C" void kernel_launch(void* const* d_in, const int* in_sizes, int n_in,
                              void* d_out, int out_size, void* d_ws, size_t ws_size,
                              hipStream_t stream) {
    const int Bn = 4, SQ = 2048, SK = 2048, D = 1024;
    const size_t nQ = (size_t)Bn * SQ * D;   // 8,388,608

    const void* qh = d_in[0];
    const void* mh = d_in[1];
    const void* mask = d_in[2];
    const void* q_w = d_in[3];
    const void* q_b = d_in[4];
    const void* k_w = d_in[5];
    const void* k_b = d_in[6];
    const void* v_w = d_in[7];
    const void* v_b = d_in[8];
    const void* o_w = d_in[9];
    const void* o_b = d_in[10];
    const void* q_kern = d_in[11];
    const void* q_cb   = d_in[12];
    const void* q_g    = d_in[13];
    const void* k_kern = d_in[14];
    const void* k_cb   = d_in[15];
    const void* k_g    = d_in[16];
    const void* v_kern = d_in[17];
    const void* v_cb   = d_in[18];
    const void* v_g    = d_in[19];

    // ---- workspace layout (lifetime-overlaid) ----
    // [0,33.5MB)        scores -> attn_out; par16/tgf live in the last 32KB
    //                   of this region from step 1 until k_convs (step 3),
    //                   clobbered only when scores is written (step 5)
    // [33.5,41.9MB)     w16 x4
    // [41.9,92.3MB)     lin_q + lin_kv; probs overlays after convs
    // [92.3,125.8MB)    qh16/mh16 staging -> conv_q, conv_k
    // [125.8,142.6MB)   vt  (must NOT alias lin_kv)
    // [142.6MB+)        flags
    char* ws = (char*)d_ws;
    _Float16* scores   = (_Float16*)(ws + 0);
    _Float16* attn_out = (_Float16*)(ws + 0);
    _Float16* par16    = (_Float16*)(ws + 33521664);          // 33.5MB - 32KB
    float*    tgf      = (float*)(ws + 33521664 + 24576);
    _Float16* w16      = (_Float16*)(ws + 33554432);
    _Float16* lin      = (_Float16*)(ws + 41943040);
    _Float16* lin_q    = lin;
    _Float16* lin_kv   = lin + nQ;
    _Float16* probs    = lin;
    _Float16* conv     = (_Float16*)(ws + 92274688);
    _Float16* qh16     = conv;
    _Float16* mh16     = conv + nQ;
    _Float16* vt       = (_Float16*)(ws + 125829120);
    int*      flags    = (int*)(ws + 142606336);

    // 0. probes
    Probe16 pa;
    const void* pp[16] = {qh, mh, q_w, k_w, v_w, o_w, q_kern, k_kern, v_kern,
                          q_b, k_b, v_b, o_b, q_cb, k_cb, v_cb};
    const int   pn[16] = {2048, 2048, 2048, 2048, 2048, 2048, 3072, 3072, 3072,
                          1024, 1024, 1024, 1024, 1024, 1024, 1024};
    for (int i = 0; i < 16; ++i) { pa.p[i] = (const unsigned short*)pp[i]; pa.n[i] = pn[i]; }
    k_probes<<<17, 256, 0, stream>>>(pa, (const unsigned int*)mask, flags);

    // 1. fused converts + conv params
    Ptr4 wp; wp.p[0] = q_w; wp.p[1] = k_w; wp.p[2] = v_w; wp.p[3] = o_w;
    ConvSrc cs;
    cs.kern[0] = q_kern; cs.kern[1] = k_kern; cs.kern[2] = v_kern;
    cs.cb[0] = q_cb; cs.cb[1] = k_cb; cs.cb[2] = v_cb;
    cs.gate[0] = q_g; cs.gate[1] = k_g; cs.gate[2] = v_g;
    k_prep<<<10241, 256, 0, stream>>>(qh, mh, qh16, wp, w16, cs, par16, tgf, flags);

    // 2. projections
    k_gemm_nt<1, 64><<<dim3(1024), 256, 0, stream>>>(
        qh16, w16, lin_q, q_b, flags + 9, nullptr, nullptr,
        D, D, 0, 0, 0, 8, 1);
    k_gemm16<1><<<dim3(256), 512, 0, stream>>>(
        mh16, w16 + (size_t)D * D, lin_kv, k_b, flags + 10, v_b, flags + 11,
        2 * D, D, 0, 0, 0, 1.0f, 8, 1);

    // 3. all three gated depthwise convs in one launch
    ConvP cq{lin_q, D, conv + 0 * nQ, par16 + 0 * 3 * D, par16 + 9 * D + 0 * D, tgf + 0};
    ConvP ck{lin_kv, 2 * D, conv + 1 * nQ, par16 + 1 * 3 * D, par16 + 9 * D + 1 * D, tgf + 1};
    k_convs<<<dim3(10240), 256, 0, stream>>>(
        cq, ck, lin_kv + D, 2 * D, vt, par16 + 2 * 3 * D, par16 + 9 * D + 2 * D, tgf + 2,
        SQ, SK, D);

    // 5. scores: per-batch M=2048 (8 tiles), N=2048 (NT=8), BZ=4 -> 256 blocks;
    //    no mask here (applied in softmax)
    k_gemm16<3><<<dim3(256), 512, 0, stream>>>(
        conv + 0 * nQ, conv + 1 * nQ, scores, nullptr, nullptr, nullptr, nullptr,
        SK, D, (long)SQ * D, (long)SK * D, (long)SQ * SK, 0.03125f, 8, 4);

    // 6. softmax + mask (coalesced raw-mask row read, width from flags[16])
    k_softmax<<<Bn * SQ, 256, 0, stream>>>(scores, probs, mask, flags + 16, SK);

    // 7. attn @ v: per-batch M=2048(64:32), N=1024 (NT=8), BZ=4 -> 1024 blocks
    k_gemm_nt<0, 64><<<dim3(1024), 256, 0, stream>>>(
        probs, vt, attn_out, nullptr, nullptr, nullptr, nullptr,
        D, SK, (long)SQ * SK, (long)D * SK, (long)SQ * D, 8, 4);

    // 8. out-proj: M=8192(64:128), N=1024 (NT=8), BZ=1 -> 1024 blocks, fp32 out
    k_gemm_nt<2, 64><<<dim3(1024), 256, 0, stream>>>(
        attn_out, w16 + 3 * (size_t)D * D, d_out, o_b, flags + 12, nullptr, nullptr,
        D, D, 0, 0, 0, 8, 1);

    (void)in_sizes; (void)n_in; (void)out_size; (void)ws_size;
}

// Round 7
// 378.943 us; speedup vs baseline: 1.1741x; 1.0391x over previous
//
#include <hip/hip_runtime.h>
#include <cstdint>
#include <cstddef>

// ---------------------------------------------------------------------------
// TransformConvCrossAttention: B=4, SQ=SK=2048, D=1024, Kconv=3
// fp16 compute, fp32 MFMA accumulation; fp32 in/out (runtime-verified).
// R17: R16 + memory-level parallelism for the streaming kernels (R16 profile:
//      k_prep at 1.84 TB/s = latency-bound, 1 load/thread).
//        k_prep:    4 chunks/thread, loads issued before converts (grid 2561)
//        k_softmax: wave-per-row, 4 rows/block, shfl-only reduction (grid 2048)
//        k_convs:   dwconv 2 rows/thread (rows s-1..s+2 -> 2 outputs)
//      GEMM kernels byte-identical to R16.
// ---------------------------------------------------------------------------

#define GLOBAL_AS __attribute__((address_space(1)))
#define LDS_AS    __attribute__((address_space(3)))

typedef _Float16 h8 __attribute__((ext_vector_type(8)));
typedef float    f4_t __attribute__((ext_vector_type(4)));
typedef unsigned short us8 __attribute__((ext_vector_type(8)));
typedef unsigned int u32x4 __attribute__((ext_vector_type(4)));

__device__ __forceinline__ float bf2f(unsigned short u) {
    union { unsigned int i; float f; } x; x.i = ((unsigned int)u) << 16; return x.f;
}
__device__ __forceinline__ float rd(const void* p, long i, int isBf) {
    return isBf ? bf2f(((const unsigned short*)p)[i]) : ((const float*)p)[i];
}

// ---------------------------------------------------------------------------
// Probes: blocks 0..15 = dtype sniff per tensor; block 16 = mask width.
struct Probe16 { const unsigned short* p[16]; int n[16]; };

__global__ void k_probes(Probe16 a, const unsigned int* __restrict__ mask,
                         int* __restrict__ flags) {
    if (blockIdx.x < 16) {
        __shared__ int cnt;
        if (threadIdx.x == 0) cnt = 0;
        __syncthreads();
        const unsigned short* s = a.p[blockIdx.x];
        const int n = a.n[blockIdx.x];
        int bad = 0;
        for (int i = threadIdx.x; i < n; i += 256) {
            int e = (s[i] >> 7) & 0xFF;
            if (e >= 0x8F || (e > 0 && e <= 0x60)) bad++;
        }
        atomicAdd(&cnt, bad);
        __syncthreads();
        if (threadIdx.x == 0) flags[blockIdx.x] = (cnt * 4 > n) ? 0 : 1;
    } else {
        __shared__ int vi32, vf32, vbf, vf16;
        if (threadIdx.x == 0) { vi32 = vf32 = vbf = vf16 = 0; }
        __syncthreads();
        int bi32 = 0, bf32 = 0, bbf = 0, bf16c = 0;
        for (int i = threadIdx.x; i < 4096; i += 256) {
            unsigned int w = mask[i];
            if (!(w == 0u || w == 1u)) bi32++;
            if (!(w == 0u || w == 0x3F800000u)) bf32++;
            unsigned int h0 = w & 0xFFFFu, h1 = w >> 16;
            if (!((h0 == 0u || h0 == 0x3F80u) && (h1 == 0u || h1 == 0x3F80u))) bbf++;
            if (!((h0 == 0u || h0 == 0x3C00u) && (h1 == 0u || h1 == 0x3C00u))) bf16c++;
        }
        if (bi32) atomicAdd(&vi32, 1);
        if (bf32) atomicAdd(&vf32, 1);
        if (bbf)  atomicAdd(&vbf, 1);
        if (bf16c) atomicAdd(&vf16, 1);
        __syncthreads();
        if (threadIdx.x == 0) {
            int w;
            if (vi32 == 0) w = 4;
            else if (vf32 == 0) w = 4;
            else if (vbf == 0) w = 2;
            else if (vf16 == 0) w = 2;
            else w = 1;
            flags[16] = w;
        }
    }
}

// ---------------------------------------------------------------------------
struct Ptr4 { const void* p[4]; };
struct ConvSrc { const void* kern[3]; const void* cb[3]; const void* gate[3]; };

// ---------------------------------------------------------------------------
// k_prep: fused converts + conv params, 4 chunks (h8) per thread with the
// loads issued before any convert/store (4-8 outstanding 16B loads).
// Grid 2561 x 256 thr:
//   [0, 2048)   qh|mh -> fp16.  Block covers 1024 consecutive h8; tensor
//               boundary at block granularity (2^20 h8/tensor, /1024 = 1024).
//   [2048,2560) 4 weight mats.  (2^17 h8/tensor, /1024 = 128 blocks/tensor)
//   [2560]      conv params: kern [D,3] -> planar fp16 [3][D]; cbias; tanh(g)
__global__ void k_prep(const void* __restrict__ qh, const void* __restrict__ mh,
                       _Float16* __restrict__ h16dst,
                       Ptr4 wsrc, _Float16* __restrict__ w16dst,
                       ConvSrc cs, _Float16* __restrict__ par16,
                       float* __restrict__ tgf,
                       const int* __restrict__ flags) {
    const int bid = blockIdx.x, tid = threadIdx.x;
    if (bid < 2560) {
        const void* src;
        _Float16* dst;
        size_t base, off;
        int isBf;
        if (bid < 2048) {
            const int seg = bid >> 10;
            src = seg ? mh : qh;
            isBf = flags[seg];
            base = (size_t)bid * 1024 + tid;
            off = base & 1048575;
            dst = h16dst;
        } else {
            const int lb = bid - 2048;
            const int seg = lb >> 7;
            src = wsrc.p[seg];
            isBf = flags[2 + seg];
            base = (size_t)lb * 1024 + tid;
            off = base & 131071;
            dst = w16dst;
        }
        if (isBf) {
            us8 s[4];
            const unsigned short* sp = (const unsigned short*)src;
#pragma unroll
            for (int j = 0; j < 4; ++j)
                s[j] = *(const us8*)(sp + (off + (size_t)j * 256) * 8);
#pragma unroll
            for (int j = 0; j < 4; ++j) {
                h8 d;
#pragma unroll
                for (int u = 0; u < 8; ++u) d[u] = (_Float16)bf2f(s[j][u]);
                *(h8*)(dst + (base + (size_t)j * 256) * 8) = d;
            }
        } else {
            f4_t a[4], b[4];
            const float* fp = (const float*)src;
#pragma unroll
            for (int j = 0; j < 4; ++j) {
                a[j] = *(const f4_t*)(fp + (off + (size_t)j * 256) * 8);
                b[j] = *(const f4_t*)(fp + (off + (size_t)j * 256) * 8 + 4);
            }
#pragma unroll
            for (int j = 0; j < 4; ++j) {
                h8 d;
#pragma unroll
                for (int u = 0; u < 4; ++u) {
                    d[u] = (_Float16)a[j][u];
                    d[4 + u] = (_Float16)b[j][u];
                }
                *(h8*)(dst + (base + (size_t)j * 256) * 8) = d;
            }
        }
    } else {
        const int D = 1024;
#pragma unroll
        for (int t = 0; t < 3; ++t) {
            const int kIs = flags[6 + t], cIs = flags[13 + t];
            for (int d = tid; d < D; d += 256) {
#pragma unroll
                for (int j = 0; j < 3; ++j)
                    par16[t * 3 * D + j * D + d] = (_Float16)rd(cs.kern[t], (long)d * 3 + j, kIs);
                par16[9 * D + t * D + d] = (_Float16)rd(cs.cb[t], d, cIs);
            }
        }
        if (tid < 3) {
            const void* g = cs.gate[tid];
            float gv = rd(g, 0, ((const unsigned int*)g)[0] == 0u ? 1 : 0);
            tgf[tid] = tanhf(gv);
        }
    }
}

// ---------------------------------------------------------------------------
// R10 NT GEMM (proven 753 TF class), MTILE x 128 x BK=64, 4 waves/block,
// 24KB LDS -> 4 blocks/CU with __launch_bounds__(256,4).
// MODE 0: fp16 out  MODE 1: fp16 out + bias  MODE 2: fp32 out + bias
template <int MODE, int MTILE>
__global__ __launch_bounds__(256, 4) void k_gemm_nt(
    const _Float16* __restrict__ A, const _Float16* __restrict__ Bm,
    void* __restrict__ Cout,
    const void* __restrict__ bias, const int* __restrict__ biasFlag,
    const void* __restrict__ bias2, const int* __restrict__ biasFlag2,
    int N, int K, long sA, long sB, long sC,
    int NT, int BZ) {

    constexpr int NI = (MTILE == 128) ? 4 : 2;
    constexpr int NCA = MTILE / 32;
    __shared__ __align__(16) _Float16 As[MTILE * 64];
    __shared__ __align__(16) _Float16 Bs[128 * 64];

    const long id = blockIdx.x;
    const int xcd = (int)(id & 7);
    const long local = id >> 3;
    const int col = (int)(local % NT);
    const long g = (local / NT) * 8 + xcd;
    const int bz = (int)(g % BZ);
    const int brow = (int)(g / BZ);

    const int tid  = threadIdx.x;
    const int wave = tid >> 6, lane = tid & 63;
    const int wm = (wave >> 1) * (MTILE / 2), wn = (wave & 1) * 64;
    const int lr = lane & 15, lq = lane >> 4;

    const _Float16* Ab = A + (long)bz * sA + (size_t)brow * MTILE * K;
    const _Float16* Bb = Bm + (long)bz * sB + (size_t)col * 128 * K;

    f4_t acc[NI][4] = {};

    const _Float16* gA[NCA];
    _Float16* lA[NCA];
#pragma unroll
    for (int j = 0; j < NCA; ++j) {
        int c = tid + j * 256;
        int r = c >> 3, s = ((c & 7) - r) & 7;
        gA[j] = Ab + (size_t)r * K + s * 8;
        lA[j] = As + c * 8;
    }
    const _Float16* gB[4];
    _Float16* lB[4];
#pragma unroll
    for (int j = 0; j < 4; ++j) {
        int c = tid + j * 256;
        int r = c >> 3, s = ((c & 7) - r) & 7;
        gB[j] = Bb + (size_t)r * K + s * 8;
        lB[j] = Bs + c * 8;
    }

    for (int kb = 0; kb < K; kb += 64) {
#pragma unroll
        for (int j = 0; j < NCA; ++j)
            __builtin_amdgcn_global_load_lds((void GLOBAL_AS*)(gA[j] + kb), (void LDS_AS*)lA[j], 16, 0, 0);
#pragma unroll
        for (int j = 0; j < 4; ++j)
            __builtin_amdgcn_global_load_lds((void GLOBAL_AS*)(gB[j] + kb), (void LDS_AS*)lB[j], 16, 0, 0);
        __syncthreads();

#pragma unroll
        for (int t = 0; t < 2; ++t) {
            const int fs = ((t * 4 + lq + lr) & 7) * 8;
            h8 af[NI], bfr[4];
#pragma unroll
            for (int i = 0; i < NI; ++i) af[i]  = *(const h8*)&As[(wm + i * 16 + lr) * 64 + fs];
#pragma unroll
            for (int j = 0; j < 4; ++j) bfr[j] = *(const h8*)&Bs[(wn + j * 16 + lr) * 64 + fs];
#pragma unroll
            for (int i = 0; i < NI; ++i)
#pragma unroll
                for (int j = 0; j < 4; ++j)
                    acc[i][j] = __builtin_amdgcn_mfma_f32_16x16x32_f16(af[i], bfr[j], acc[i][j], 0, 0, 0);
        }
        __syncthreads();
    }

    const long row0 = (long)brow * MTILE + wm + lq * 4;
    const long col0 = (long)col * 128 + wn + lr;

    float bv[4];
    if constexpr (MODE != 0) {
        const void* bp = bias; const int* bfp = biasFlag; long boff = 0;
        if (bias2 != nullptr && col * 128 >= (N >> 1)) {
            bp = bias2; bfp = biasFlag2; boff = (long)(N >> 1);
        }
        const int bIs = *bfp;
#pragma unroll
        for (int j = 0; j < 4; ++j) bv[j] = rd(bp, col0 + j * 16 - boff, bIs);
    } else {
#pragma unroll
        for (int j = 0; j < 4; ++j) bv[j] = 0.0f;
    }
    if constexpr (MODE == 2) {
        float* C = (float*)Cout + (long)bz * sC;
#pragma unroll
        for (int i = 0; i < NI; ++i)
#pragma unroll
            for (int j = 0; j < 4; ++j)
#pragma unroll
                for (int r = 0; r < 4; ++r)
                    C[(row0 + i * 16 + r) * (long)N + col0 + j * 16] = acc[i][j][r] + bv[j];
    } else {
        _Float16* C = (_Float16*)Cout + (long)bz * sC;
#pragma unroll
        for (int i = 0; i < NI; ++i)
#pragma unroll
            for (int j = 0; j < 4; ++j)
#pragma unroll
                for (int r = 0; r < 4; ++r) {
                    float v = acc[i][j][r] + bv[j];
                    v = fminf(fmaxf(v, -65000.0f), 65000.0f);
                    C[(row0 + i * 16 + r) * (long)N + col0 + j * 16] = (_Float16)v;
                }
    }
}

// ---------------------------------------------------------------------------
// m201-family pipelined NT GEMM: 256 x 256 x BK=64, 512 thr = 8 waves (2Mx4N),
// wave out 128x64. 128KB LDS, 2 K-tile buffers, 4 phases/K-tile (C-quadrants
// of 16 MFMA), 2 global_load_lds per phase, counted vmcnt(4) at 3/4 phase
// closes (never 0 until final drain), setprio(1) around MFMA, seg-rotation
// swizzle (measured 0 conflicts). R13-verified loop.
// MODE 1: fp16 out + bias (bias2 = 2nd N-half)
// MODE 3: fp16 scores, scale+clamp only (mask applied later in softmax)
template <int MODE>
__global__ __launch_bounds__(512, 2) void k_gemm16(
    const _Float16* __restrict__ A, const _Float16* __restrict__ Bm,
    void* __restrict__ Cout,
    const void* __restrict__ bias, const int* __restrict__ biasFlag,
    const void* __restrict__ bias2, const int* __restrict__ biasFlag2,
    int N, int K, long sA, long sB, long sC,
    float scale, int NT, int BZ) {

    __shared__ __align__(16) _Float16 AS[2][2][8192];
    __shared__ __align__(16) _Float16 BS[2][2][8192];

    const long id = blockIdx.x;
    const int xcd = (int)(id & 7);
    const long local = id >> 3;
    const int col = (int)(local % NT);
    const long g = (local / NT) * 8 + xcd;
    const int bz = (int)(g % BZ);
    const int brow = (int)(g / BZ);

    const int tid  = threadIdx.x;
    const int wave = tid >> 6, lane = tid & 63;
    const int wr = wave >> 2, wc = wave & 3;
    const int lr = lane & 15, lq = lane >> 4;

    const _Float16* Ab = A + (long)bz * sA + (size_t)brow * 256 * K;
    const _Float16* Bb = Bm + (long)bz * sB + (size_t)col * 256 * K;

    f4_t acc[8][4] = {};

    const _Float16* gAsrc[2][2];
    const _Float16* gBsrc[2][2];
    int lOff[2];
#pragma unroll
    for (int j = 0; j < 2; ++j) {
        int c = tid + j * 512;
        int rho = c >> 3, s = ((c & 7) - rho) & 7;
        lOff[j] = c * 8;
#pragma unroll
        for (int gg = 0; gg < 2; ++gg) {
            int ra = gg * 64 + (rho & 63) + (rho >> 6) * 128;
            gAsrc[gg][j] = Ab + (size_t)ra * K + s * 8;
            int rb = gg * 32 + (rho & 31) + (rho >> 5) * 64;
            gBsrc[gg][j] = Bb + (size_t)rb * K + s * 8;
        }
    }

#define STAGE_A(buf, gg, kb)                                                              \
    do {                                                                                  \
        __builtin_amdgcn_global_load_lds((void GLOBAL_AS*)(gAsrc[gg][0] + (kb)),          \
                                         (void LDS_AS*)&AS[buf][gg][lOff[0]], 16, 0, 0);  \
        __builtin_amdgcn_global_load_lds((void GLOBAL_AS*)(gAsrc[gg][1] + (kb)),          \
                                         (void LDS_AS*)&AS[buf][gg][lOff[1]], 16, 0, 0);  \
    } while (0)
#define STAGE_B(buf, gg, kb)                                                              \
    do {                                                                                  \
        __builtin_amdgcn_global_load_lds((void GLOBAL_AS*)(gBsrc[gg][0] + (kb)),          \
                                         (void LDS_AS*)&BS[buf][gg][lOff[0]], 16, 0, 0);  \
        __builtin_amdgcn_global_load_lds((void GLOBAL_AS*)(gBsrc[gg][1] + (kb)),          \
                                         (void LDS_AS*)&BS[buf][gg][lOff[1]], 16, 0, 0);  \
    } while (0)

    const int nkt = K >> 6;

    STAGE_A(0, 0, 0);
    STAGE_B(0, 0, 0);
    STAGE_B(0, 1, 0);
    STAGE_A(0, 1, 0);
    asm volatile("s_waitcnt vmcnt(4)" ::: "memory");
    __builtin_amdgcn_s_barrier();

    int cur = 0;
    for (int t = 0; t < nkt; ++t) {
        const bool pf = (t + 1) < nkt;
        const long kb = (long)(t + 1) << 6;
        const int nx = cur ^ 1;
        h8 a0[4][2], a1[4][2], b0[2][2], b1[2][2];

        // ---- phase 0: quadrant (0,0) ----
#pragma unroll
        for (int ks = 0; ks < 2; ++ks) {
#pragma unroll
            for (int m = 0; m < 4; ++m) {
                int rho = wr * 64 + m * 16 + lr;
                a0[m][ks] = *(const h8*)&AS[cur][0][rho * 64 + ((ks * 4 + lq + rho) & 7) * 8];
            }
#pragma unroll
            for (int n = 0; n < 2; ++n) {
                int rho = wc * 32 + n * 16 + lr;
                b0[n][ks] = *(const h8*)&BS[cur][0][rho * 64 + ((ks * 4 + lq + rho) & 7) * 8];
            }
        }
        if (pf) STAGE_A(nx, 0, kb);
        __builtin_amdgcn_s_barrier();
        __builtin_amdgcn_s_setprio(1);
#pragma unroll
        for (int ks = 0; ks < 2; ++ks)
#pragma unroll
            for (int m = 0; m < 4; ++m)
#pragma unroll
                for (int n = 0; n < 2; ++n)
                    acc[m][n] = __builtin_amdgcn_mfma_f32_16x16x32_f16(
                        a0[m][ks], b0[n][ks], acc[m][n], 0, 0, 0);
        __builtin_amdgcn_s_setprio(0);
        if (pf) asm volatile("s_waitcnt vmcnt(4)" ::: "memory");
        else    asm volatile("s_waitcnt vmcnt(2)" ::: "memory");
        __builtin_amdgcn_s_barrier();

        // ---- phase 1: quadrant (0,1) ----
#pragma unroll
        for (int ks = 0; ks < 2; ++ks)
#pragma unroll
            for (int n = 0; n < 2; ++n) {
                int rho = wc * 32 + n * 16 + lr;
                b1[n][ks] = *(const h8*)&BS[cur][1][rho * 64 + ((ks * 4 + lq + rho) & 7) * 8];
            }
        if (pf) STAGE_B(nx, 0, kb);
        __builtin_amdgcn_s_barrier();
        __builtin_amdgcn_s_setprio(1);
#pragma unroll
        for (int ks = 0; ks < 2; ++ks)
#pragma unroll
            for (int m = 0; m < 4; ++m)
#pragma unroll
                for (int n = 0; n < 2; ++n)
                    acc[m][2 + n] = __builtin_amdgcn_mfma_f32_16x16x32_f16(
                        a0[m][ks], b1[n][ks], acc[m][2 + n], 0, 0, 0);
        __builtin_amdgcn_s_setprio(0);
        if (pf) asm volatile("s_waitcnt vmcnt(4)" ::: "memory");
        else    asm volatile("s_waitcnt vmcnt(0)" ::: "memory");
        __builtin_amdgcn_s_barrier();

        // ---- phase 2: quadrant (1,1) ----
#pragma unroll
        for (int ks = 0; ks < 2; ++ks)
#pragma unroll
            for (int m = 0; m < 4; ++m) {
                int rho = wr * 64 + m * 16 + lr;
                a1[m][ks] = *(const h8*)&AS[cur][1][rho * 64 + ((ks * 4 + lq + rho) & 7) * 8];
            }
        if (pf) STAGE_B(nx, 1, kb);
        __builtin_amdgcn_s_barrier();
        __builtin_amdgcn_s_setprio(1);
#pragma unroll
        for (int ks = 0; ks < 2; ++ks)
#pragma unroll
            for (int m = 0; m < 4; ++m)
#pragma unroll
                for (int n = 0; n < 2; ++n)
                    acc[4 + m][2 + n] = __builtin_amdgcn_mfma_f32_16x16x32_f16(
                        a1[m][ks], b1[n][ks], acc[4 + m][2 + n], 0, 0, 0);
        __builtin_amdgcn_s_setprio(0);
        __builtin_amdgcn_s_barrier();

        // ---- phase 3: quadrant (1,0) ----
#pragma unroll
        for (int ks = 0; ks < 2; ++ks)
#pragma unroll
            for (int n = 0; n < 2; ++n) {
                int rho = wc * 32 + n * 16 + lr;
                b0[n][ks] = *(const h8*)&BS[cur][0][rho * 64 + ((ks * 4 + lq + rho) & 7) * 8];
            }
        if (pf) STAGE_A(nx, 1, kb);
        __builtin_amdgcn_s_barrier();
        __builtin_amdgcn_s_setprio(1);
#pragma unroll
        for (int ks = 0; ks < 2; ++ks)
#pragma unroll
            for (int m = 0; m < 4; ++m)
#pragma unroll
                for (int n = 0; n < 2; ++n)
                    acc[4 + m][n] = __builtin_amdgcn_mfma_f32_16x16x32_f16(
                        a1[m][ks], b0[n][ks], acc[4 + m][n], 0, 0, 0);
        __builtin_amdgcn_s_setprio(0);
        if (pf) asm volatile("s_waitcnt vmcnt(4)" ::: "memory");
        __builtin_amdgcn_s_barrier();
        cur = nx;
    }
#undef STAGE_A
#undef STAGE_B

    const long row0 = (long)brow * 256 + wr * 128 + lq * 4;
    const long col0 = (long)col * 256 + wc * 64 + lr;

    if constexpr (MODE == 3) {
        _Float16* C = (_Float16*)Cout + (long)bz * sC;
#pragma unroll
        for (int i = 0; i < 8; ++i)
#pragma unroll
            for (int j = 0; j < 4; ++j)
#pragma unroll
                for (int r = 0; r < 4; ++r) {
                    float v = acc[i][j][r] * scale;
                    v = fminf(fmaxf(v, -60000.0f), 60000.0f);
                    C[(row0 + i * 16 + r) * (long)N + col0 + j * 16] = (_Float16)v;
                }
    } else {
        float bv[4];
        {
            const void* bp = bias; const int* bfp = biasFlag; long boff = 0;
            if (bias2 != nullptr && col * 256 >= (N >> 1)) {
                bp = bias2; bfp = biasFlag2; boff = (long)(N >> 1);
            }
            const int bIs = *bfp;
#pragma unroll
            for (int j = 0; j < 4; ++j) bv[j] = rd(bp, col0 + j * 16 - boff, bIs);
        }
        _Float16* C = (_Float16*)Cout + (long)bz * sC;
#pragma unroll
        for (int i = 0; i < 8; ++i)
#pragma unroll
            for (int j = 0; j < 4; ++j)
#pragma unroll
                for (int r = 0; r < 4; ++r) {
                    float v = acc[i][j][r] + bv[j];
                    v = fminf(fmaxf(v, -65000.0f), 65000.0f);
                    C[(row0 + i * 16 + r) * (long)N + col0 + j * 16] = (_Float16)v;
                }
    }
}

// ---------------------------------------------------------------------------
// Fused conv launch.
// Blocks [0,4096): dwconv q (0..2047) / k (2048..4095), 4 rows/block:
//   thread-group g=tid>>7 handles rows s, s+1 (s = sp*4 + 2g) via 4 row loads
//   x[s-1..s+2] -> 2 outputs (ILP + 33% fewer loads).
// Blocks [4096,6144): dwconv_v + transpose (unchanged body).
struct ConvP {
    const _Float16* x; int xs; _Float16* y;
    const _Float16* kp; const _Float16* cb; const float* tg;
};
__global__ void k_convs(ConvP p0, ConvP p1,
                        const _Float16* __restrict__ xv, int xvs,
                        _Float16* __restrict__ vt,
                        const _Float16* __restrict__ kpv,
                        const _Float16* __restrict__ cbv,
                        const float* __restrict__ tgv,
                        int S, int SK, int D) {
    __shared__ _Float16 T[64][65];
    const int bid = blockIdx.x, tid = threadIdx.x;
    h8 zero;
#pragma unroll
    for (int u = 0; u < 8; ++u) zero[u] = (_Float16)0.0f;

    if (bid < 4096) {
        const ConvP& p = (bid >= 2048) ? p1 : p0;
        int l = bid & 2047;              // 512 blocks/batch (2048 rows / 4)
        int b = l >> 9, sp = l & 511;
        int g = tid >> 7;                // 0,1
        int s = sp * 4 + g * 2;          // first row of this thread's pair
        int d0 = (tid & 127) * 8;
        const size_t rs = p.xs;
        const size_t xb = ((size_t)b * S + s) * rs + d0;
        // rows s-1, s, s+1, s+2 (s+1 <= 2047 always; guards on s-1, s+2)
        h8 xA = (s > 0) ? *(const h8*)(p.x + xb - rs) : zero;
        h8 xB = *(const h8*)(p.x + xb);
        h8 xC = *(const h8*)(p.x + xb + rs);
        h8 xD = (s + 2 < S) ? *(const h8*)(p.x + xb + 2 * rs) : zero;
        h8 k0 = *(const h8*)(p.kp + 0 * D + d0);
        h8 k1 = *(const h8*)(p.kp + 1 * D + d0);
        h8 k2 = *(const h8*)(p.kp + 2 * D + d0);
        h8 cb = *(const h8*)(p.cb + d0);
        float tg = *p.tg;
        h8 o0, o1;
#pragma unroll
        for (int u = 0; u < 8; ++u) {
            float c0 = (float)xA[u] * (float)k0[u] + (float)xB[u] * (float)k1[u] +
                       (float)xC[u] * (float)k2[u] + (float)cb[u];
            float v0 = (float)xB[u] + tg * c0;
            o0[u] = (_Float16)fminf(fmaxf(v0, -65000.0f), 65000.0f);
            float c1 = (float)xB[u] * (float)k0[u] + (float)xC[u] * (float)k1[u] +
                       (float)xD[u] * (float)k2[u] + (float)cb[u];
            float v1 = (float)xC[u] + tg * c1;
            o1[u] = (_Float16)fminf(fmaxf(v1, -65000.0f), 65000.0f);
        }
        const size_t yb = ((size_t)b * S + s) * D + d0;
        *(h8*)(p.y + yb) = o0;
        *(h8*)(p.y + yb + D) = o1;
    } else {
        int l = bid - 4096;
        int bx = l & 31, by = (l >> 5) & 15, b = l >> 9;
        int s0 = bx * 64, d0 = by * 64;
        float tg = *tgv;
#pragma unroll
        for (int it = 0; it < 2; ++it) {
            int idx = it * 256 + tid;
            int r = idx >> 3, c = (idx & 7) * 8;
            int s = s0 + r;
            const size_t xb = ((size_t)b * SK + s) * xvs + d0 + c;
            h8 xc = *(const h8*)(xv + xb);
            h8 xp = (s > 0)      ? *(const h8*)(xv + xb - xvs) : zero;
            h8 xn = (s < SK - 1) ? *(const h8*)(xv + xb + xvs) : zero;
            h8 k0 = *(const h8*)(kpv + 0 * D + d0 + c);
            h8 k1 = *(const h8*)(kpv + 1 * D + d0 + c);
            h8 k2 = *(const h8*)(kpv + 2 * D + d0 + c);
            h8 cb = *(const h8*)(cbv + d0 + c);
#pragma unroll
            for (int u = 0; u < 8; ++u) {
                float cv = (float)xp[u] * (float)k0[u] + (float)xc[u] * (float)k1[u] +
                           (float)xn[u] * (float)k2[u] + (float)cb[u];
                float v = (float)xc[u] + tg * cv;
                T[r][c + u] = (_Float16)fminf(fmaxf(v, -65000.0f), 65000.0f);
            }
        }
        __syncthreads();
#pragma unroll
        for (int it = 0; it < 2; ++it) {
            int idx = it * 256 + tid;
            int dr = idx >> 3, c = (idx & 7) * 8;
            h8 o;
#pragma unroll
            for (int u = 0; u < 8; ++u) o[u] = T[c + u][dr];
            *(h8*)(vt + ((size_t)b * D + d0 + dr) * SK + s0 + c) = o;
        }
    }
}

// ---------------------------------------------------------------------------
// Row softmax + mask, wave-per-row: 4 rows/block (grid = B*SQ/4), lane owns
// 4 interleaved h8 chunks (chunk c = j*64+lane -> fully coalesced 1KB/instr).
// Pure __shfl_xor 64-lane reduction: no LDS, no __syncthreads.
// Mask row = row & (SQ-1); element width in *mwf (1/2/4 bytes).
__global__ __launch_bounds__(256) void k_softmax(const _Float16* __restrict__ sc,
                                                 _Float16* __restrict__ pr,
                                                 const void* __restrict__ mraw,
                                                 const int* __restrict__ mwf,
                                                 int SK) {
    const long row = (long)blockIdx.x * 4 + (threadIdx.x >> 6);
    const int lane = threadIdx.x & 63;
    const long rb = row * (long)SK;
    const long mrb = (row & 2047) * (long)SK;
    const int mw = *mwf;

    h8 v[4];
#pragma unroll
    for (int j = 0; j < 4; ++j)
        v[j] = *(const h8*)(sc + rb + (size_t)(j * 64 + lane) * 8);

    unsigned int km[4];
    if (mw == 4) {
#pragma unroll
        for (int j = 0; j < 4; ++j) {
            const unsigned int* mp = (const unsigned int*)mraw + mrb + (size_t)(j * 64 + lane) * 8;
            u32x4 m0 = *(const u32x4*)mp;
            u32x4 m1 = *(const u32x4*)(mp + 4);
            unsigned int k = 0;
#pragma unroll
            for (int u = 0; u < 4; ++u) {
                k |= (m0[u] != 0u) ? (1u << u) : 0u;
                k |= (m1[u] != 0u) ? (1u << (4 + u)) : 0u;
            }
            km[j] = k;
        }
    } else if (mw == 2) {
#pragma unroll
        for (int j = 0; j < 4; ++j) {
            us8 m8 = *(const us8*)((const unsigned short*)mraw + mrb + (size_t)(j * 64 + lane) * 8);
            unsigned int k = 0;
#pragma unroll
            for (int u = 0; u < 8; ++u) k |= (m8[u] != 0) ? (1u << u) : 0u;
            km[j] = k;
        }
    } else {
#pragma unroll
        for (int j = 0; j < 4; ++j) {
            unsigned long long m = *(const unsigned long long*)
                ((const unsigned char*)mraw + mrb + (size_t)(j * 64 + lane) * 8);
            unsigned int k = 0;
#pragma unroll
            for (int u = 0; u < 8; ++u) k |= ((m >> (8 * u)) & 0xFFull) ? (1u << u) : 0u;
            km[j] = k;
        }
    }

    float f[4][8];
    float mx = -3.0e38f;
#pragma unroll
    for (int j = 0; j < 4; ++j)
#pragma unroll
        for (int u = 0; u < 8; ++u) {
            f[j][u] = (km[j] & (1u << u)) ? (float)v[j][u] : -60000.0f;
            mx = fmaxf(mx, f[j][u]);
        }
#pragma unroll
    for (int o = 32; o > 0; o >>= 1) mx = fmaxf(mx, __shfl_xor(mx, o, 64));

    float sum = 0.0f;
#pragma unroll
    for (int j = 0; j < 4; ++j)
#pragma unroll
        for (int u = 0; u < 8; ++u) { f[j][u] = __expf(f[j][u] - mx); sum += f[j][u]; }
#pragma unroll
    for (int o = 32; o > 0; o >>= 1) sum += __shfl_xor(sum, o, 64);
    const float inv = 1.0f / sum;

#pragma unroll
    for (int j = 0; j < 4; ++j) {
        h8 o8;
#pragma unroll
        for (int u = 0; u < 8; ++u) o8[u] = (_Float16)(f[j][u] * inv);
        *(h8*)(pr + rb + (size_t)(j * 64 + lane) * 8) = o8;
    }
}

// ---------------------------------------------------------------------------
extern "C" void kernel_launch(void* const* d_in, const int* in_sizes, int n_in,
                              void* d_out, int out_size, void* d_ws, size_t ws_size,
                              hipStream_t stream) {
    const int Bn = 4, SQ = 2048, SK = 2048, D = 1024;
    const size_t nQ = (size_t)Bn * SQ * D;   // 8,388,608

    const void* qh = d_in[0];
    const void* mh = d_in[1];
    const void* mask = d_in[2];
    const void* q_w = d_in[3];
    const void* q_b = d_in[4];
    const void* k_w = d_in[5];
    const void* k_b = d_in[6];
    const void* v_w = d_in[7];
    const void* v_b = d_in[8];
    const void* o_w = d_in[9];
    const void* o_b = d_in[10];
    const void* q_kern = d_in[11];
    const void* q_cb   = d_in[12];
    const void* q_g    = d_in[13];
    const void* k_kern = d_in[14];
    const void* k_cb   = d_in[15];
    const void* k_g    = d_in[16];
    const void* v_kern = d_in[17];
    const void* v_cb   = d_in[18];
    const void* v_g    = d_in[19];

    // ---- workspace layout (lifetime-overlaid) ----
    // [0,33.5MB)        scores -> attn_out; par16/tgf live in the last 32KB
    //                   of this region from step 1 until k_convs (step 3),
    //                   clobbered only when scores is written (step 5)
    // [33.5,41.9MB)     w16 x4
    // [41.9,92.3MB)     lin_q + lin_kv; probs overlays after convs
    // [92.3,125.8MB)    qh16/mh16 staging -> conv_q, conv_k
    // [125.8,142.6MB)   vt  (must NOT alias lin_kv)
    // [142.6MB+)        flags
    char* ws = (char*)d_ws;
    _Float16* scores   = (_Float16*)(ws + 0);
    _Float16* attn_out = (_Float16*)(ws + 0);
    _Float16* par16    = (_Float16*)(ws + 33521664);          // 33.5MB - 32KB
    float*    tgf      = (float*)(ws + 33521664 + 24576);
    _Float16* w16      = (_Float16*)(ws + 33554432);
    _Float16* lin      = (_Float16*)(ws + 41943040);
    _Float16* lin_q    = lin;
    _Float16* lin_kv   = lin + nQ;
    _Float16* probs    = lin;
    _Float16* conv     = (_Float16*)(ws + 92274688);
    _Float16* qh16     = conv;
    _Float16* mh16     = conv + nQ;
    _Float16* vt       = (_Float16*)(ws + 125829120);
    int*      flags    = (int*)(ws + 142606336);

    // 0. probes
    Probe16 pa;
    const void* pp[16] = {qh, mh, q_w, k_w, v_w, o_w, q_kern, k_kern, v_kern,
                          q_b, k_b, v_b, o_b, q_cb, k_cb, v_cb};
    const int   pn[16] = {2048, 2048, 2048, 2048, 2048, 2048, 3072, 3072, 3072,
                          1024, 1024, 1024, 1024, 1024, 1024, 1024};
    for (int i = 0; i < 16; ++i) { pa.p[i] = (const unsigned short*)pp[i]; pa.n[i] = pn[i]; }
    k_probes<<<17, 256, 0, stream>>>(pa, (const unsigned int*)mask, flags);

    // 1. fused converts + conv params (4 chunks/thread)
    Ptr4 wp; wp.p[0] = q_w; wp.p[1] = k_w; wp.p[2] = v_w; wp.p[3] = o_w;
    ConvSrc cs;
    cs.kern[0] = q_kern; cs.kern[1] = k_kern; cs.kern[2] = v_kern;
    cs.cb[0] = q_cb; cs.cb[1] = k_cb; cs.cb[2] = v_cb;
    cs.gate[0] = q_g; cs.gate[1] = k_g; cs.gate[2] = v_g;
    k_prep<<<2561, 256, 0, stream>>>(qh, mh, qh16, wp, w16, cs, par16, tgf, flags);

    // 2. projections
    k_gemm_nt<1, 64><<<dim3(1024), 256, 0, stream>>>(
        qh16, w16, lin_q, q_b, flags + 9, nullptr, nullptr,
        D, D, 0, 0, 0, 8, 1);
    k_gemm16<1><<<dim3(256), 512, 0, stream>>>(
        mh16, w16 + (size_t)D * D, lin_kv, k_b, flags + 10, v_b, flags + 11,
        2 * D, D, 0, 0, 0, 1.0f, 8, 1);

    // 3. all three gated depthwise convs in one launch (2 rows/thread)
    ConvP cq{lin_q, D, conv + 0 * nQ, par16 + 0 * 3 * D, par16 + 9 * D + 0 * D, tgf + 0};
    ConvP ck{lin_kv, 2 * D, conv + 1 * nQ, par16 + 1 * 3 * D, par16 + 9 * D + 1 * D, tgf + 1};
    k_convs<<<dim3(6144), 256, 0, stream>>>(
        cq, ck, lin_kv + D, 2 * D, vt, par16 + 2 * 3 * D, par16 + 9 * D + 2 * D, tgf + 2,
        SQ, SK, D);

    // 5. scores: per-batch M=2048 (8 tiles), N=2048 (NT=8), BZ=4 -> 256 blocks
    k_gemm16<3><<<dim3(256), 512, 0, stream>>>(
        conv + 0 * nQ, conv + 1 * nQ, scores, nullptr, nullptr, nullptr, nullptr,
        SK, D, (long)SQ * D, (long)SK * D, (long)SQ * SK, 0.03125f, 8, 4);

    // 6. softmax + mask, wave-per-row
    k_softmax<<<Bn * SQ / 4, 256, 0, stream>>>(scores, probs, mask, flags + 16, SK);

    // 7. attn @ v: per-batch M=2048(64:32), N=1024 (NT=8), BZ=4 -> 1024 blocks
    k_gemm_nt<0, 64><<<dim3(1024), 256, 0, stream>>>(
        probs, vt, attn_out, nullptr, nullptr, nullptr, nullptr,
        D, SK, (long)SQ * SK, (long)D * SK, (long)SQ * D, 8, 4);

    // 8. out-proj: M=8192(64:128), N=1024 (NT=8), BZ=1 -> 1024 blocks, fp32 out
    k_gemm_nt<2, 64><<<dim3(1024), 256, 0, stream>>>(
        attn_out, w16 + 3 * (size_t)D * D, d_out, o_b, flags + 12, nullptr, nullptr,
        D, D, 0, 0, 0, 8, 1);

    (void)in_sizes; (void)n_in; (void)out_size; (void)ws_size;
}